// Round 10
// baseline (4287.227 us; speedup 1.0000x reference)
//
#include <hip/hip_runtime.h>
#include <hip/hip_bf16.h>
#include <stdint.h>
#include <stddef.h>

#define TPAD 320   // padded time stride (300 real + 20 pad)
#define TREAL 300

// Python-f64 pool weight: float(1.1*10.0)  (validated exact, rounds 7-9)
#define POOL_W   11.000000000000002

static __device__ __forceinline__ float bf2f(uint16_t b) {
    return __uint_as_float(((uint32_t)b) << 16);
}

// ---------------------------------------------------------------------------
// f64 truncated-alpha IIR + refractory scan (validated exact, rounds 8/9).
// ---------------------------------------------------------------------------
struct IIRC { double DD, C1, C2, C3, DR; };
static __device__ __forceinline__ IIRC iirc_make() {
    IIRC c;
    c.DD = exp(-0.1);
    c.C1 = exp(1.0) / 10.0;
    c.C2 = exp(-9.0) / 10.0;
    c.C3 = 10.0 * exp(-9.0);
    c.DR = exp(-1.0);
    return c;
}
struct IIRS { double P, Q, P2, Q2, r; };
static __device__ __forceinline__ void iirs_init(IIRS& s) {
    s.P = 0.0; s.Q = 0.0; s.P2 = 0.0; s.Q2 = 0.0; s.r = 0.0;
}
static __device__ __forceinline__ bool iir_step(const IIRC& c, IIRS& st,
                                                double x, double xd) {
    double Qn  = c.DD * (st.Q + st.P);
    double Pn  = fma(c.DD, st.P, x);
    double Q2n = c.DD * (st.Q2 + st.P2);
    double P2n = fma(c.DD, st.P2, xd);
    double a = c.C1 * Qn - c.C2 * Q2n - c.C3 * P2n;
    double u = a + st.r;
    bool s = (u >= 10.0);
    st.r = c.DR * (st.r - (s ? 20.0 : 0.0));
    st.P = Pn; st.Q = Qn; st.P2 = P2n; st.Q2 = Q2n;
    return s;
}

// ---------------------------------------------------------------------------
__global__ void detect_kernel(const uint16_t* __restrict__ w1raw, int* __restrict__ flag)
{
    if (threadIdx.x == 0 && blockIdx.x == 0) {
        int sane = 1;
        for (int i = 0; i < 800; ++i) {
            int e = (w1raw[i] >> 7) & 0xFF;
            if (e >= 131) { sane = 0; break; }
        }
        *flag = sane;   // 1 = bf16, 0 = f32
    }
}

// Weight convert -> f64 ws copy (bf16->f64 exact); enables s_load_dwordx2 use.
__global__ __launch_bounds__(256) void wcvt64_kernel(
    const void* __restrict__ w, double* __restrict__ out, int n, const int* __restrict__ flag)
{
    int i = blockIdx.x * 256 + threadIdx.x;
    if (i >= n) return;
    out[i] = (*flag) ? (double)bf2f(((const uint16_t*)w)[i])
                     : (double)((const float*)w)[i];
}

// Weight convert -> f32 ws copy (for dense kernel; bf16->f32 exact)
__global__ __launch_bounds__(256) void wcvt_kernel(
    const void* __restrict__ w, float* __restrict__ out, int n, const int* __restrict__ flag)
{
    int i = blockIdx.x * 256 + threadIdx.x;
    if (i >= n) return;
    out[i] = (*flag) ? bf2f(((const uint16_t*)w)[i]) : ((const float*)w)[i];
}

__global__ __launch_bounds__(320) void convert_kernel(
    const void* __restrict__ s_in, uint8_t* __restrict__ u8, const int* __restrict__ flag)
{
    int row = blockIdx.x;
    int t = threadIdx.x;
    uint8_t v = 0;
    if (t < TREAL) {
        float x = (*flag) ? bf2f(((const uint16_t*)s_in)[(size_t)row * TREAL + t])
                          : ((const float*)s_in)[(size_t)row * TREAL + t];
        v = (x >= 0.5f) ? 1 : 0;
    }
    u8[(size_t)row * TPAD + t] = v;
}

// ---------------------------------------------------------------------------
// FUSED conv + PSP + spike scan.  Block = one (b, h, w, 16-co group).
// 320 t-lanes: conv into acc[16] f64 (weights via block-uniform s_load), z to
// bank-padded LDS, lanes 0..15 run the serial IIR scan (one co each), all
// lanes write spike bytes.  z never touches global memory.
// Grid: (Ho*Wo, Co_total/16, B)
// ---------------------------------------------------------------------------
template<int Ci, int K, int Hi>
__global__ __launch_bounds__(320) void conv_psp_kernel(
    const uint8_t* __restrict__ sprev,   // [B][Ci][Hi][Wi][TPAD]
    const double* __restrict__ Wg,       // [Co_total][Ci*K*K] f64 (exact bf16)
    uint8_t* __restrict__ sout,          // [B][Co_total][Ho][Wo][TPAD]
    int Co_total)
{
    constexpr int P = 1;
    constexpr int Wi = Hi;
    constexpr int Ho = Hi + 2 * P - K + 1;
    constexpr int Wo = Ho;
    constexpr int CKK = Ci * K * K;
    constexpr int CoB = 16;

    __shared__ double zlds[CoB][TPAD + 1];   // +1: row stride 321*8 -> lanes land on distinct banks in column reads
    __shared__ uint8_t sb[CoB][TPAD + 4];

    const int t  = threadIdx.x;              // 0..319 (t >= 300 computes pad, never scanned)
    const int h  = (int)blockIdx.x / Wo;
    const int w  = (int)blockIdx.x % Wo;
    const int co0 = (int)blockIdx.y * CoB;
    const int b  = (int)blockIdx.z;

    double acc[CoB];
    #pragma unroll
    for (int c = 0; c < CoB; ++c) acc[c] = 0.0;

    const size_t in_b = (size_t)b * Ci * Hi * Wi * TPAD;
    const double* wbase = Wg + (size_t)co0 * CKK;

    for (int ci = 0; ci < Ci; ++ci) {
        #pragma unroll
        for (int ky = 0; ky < K; ++ky) {
            const int row = h - P + ky;
            if ((unsigned)row >= (unsigned)Hi) continue;     // block-uniform
            #pragma unroll
            for (int kx = 0; kx < K; ++kx) {
                const int col = w - P + kx;
                if ((unsigned)col >= (unsigned)Wi) continue; // block-uniform
                uint8_t bv = sprev[in_b + (((size_t)ci * Hi + row) * Wi + col) * TPAD + t];
                if (__any(bv != 0)) {     // silent 64-t window: fma(w,0,acc)==acc exactly
                    const double x = (double)bv;
                    const double* wp = wbase + (ci * K + ky) * K + kx;  // uniform -> s_load
                    #pragma unroll
                    for (int c = 0; c < CoB; ++c)
                        acc[c] = fma(wp[(size_t)c * CKK], x, acc[c]);
                }
            }
        }
    }

    #pragma unroll
    for (int c = 0; c < CoB; ++c) zlds[c][t] = acc[c];
    #pragma unroll
    for (int c = 0; c < CoB; ++c) sb[c][t] = 0;
    __syncthreads();

    if (t < CoB) {   // lane t scans co = t
        const IIRC cc = iirc_make();
        IIRS st; iirs_init(st);
        for (int i = 0; i < TREAL; ++i) {
            double xd = (i >= 100) ? zlds[t][i - 100] : 0.0;
            sb[t][i] = iir_step(cc, st, zlds[t][i], xd) ? 1 : 0;
        }
    }
    __syncthreads();

    #pragma unroll
    for (int c = 0; c < CoB; ++c) {
        size_t off = ((((size_t)b * Co_total + co0 + c) * Ho + h) * Wo + w) * TPAD + t;
        sout[off] = sb[c][t];
    }
}

// ---------------------------------------------------------------------------
// Fused pool(2x2, w=POOL_W) + IIR-PSP + scan (validated rounds 8/9).
// ---------------------------------------------------------------------------
template<int C, int Hi>
__global__ __launch_bounds__(256) void pool_psp_iir_kernel(
    const uint8_t* __restrict__ sprev, uint8_t* __restrict__ sout, int N)
{
    constexpr int Wi = Hi, Ho = Hi / 2, Wo = Wi / 2;
    int n = blockIdx.x * 256 + threadIdx.x;
    if (n >= N) return;
    int wo = n % Wo;  int r1 = n / Wo;
    int ho = r1 % Ho; int r2 = r1 / Ho;
    int cc = r2 % C;  int b  = r2 / C;
    const uint8_t* p0 = sprev + ((((size_t)b * C + cc) * Hi + 2 * ho) * Wi + 2 * wo) * TPAD;
    const uint8_t* p1 = p0 + TPAD;
    const uint8_t* p2 = p0 + (size_t)Wi * TPAD;
    const uint8_t* p3 = p2 + TPAD;
    uint8_t* sr = sout + (size_t)n * TPAD;
    const IIRC c = iirc_make();
    IIRS st; iirs_init(st);
    for (int t0 = 0; t0 < TREAL; t0 += 4) {
        uint32_t a0 = *(const uint32_t*)(p0 + t0), a1 = *(const uint32_t*)(p1 + t0);
        uint32_t a2 = *(const uint32_t*)(p2 + t0), a3 = *(const uint32_t*)(p3 + t0);
        uint32_t d0 = 0, d1 = 0, d2 = 0, d3 = 0;
        if (t0 >= 100) {
            d0 = *(const uint32_t*)(p0 + t0 - 100); d1 = *(const uint32_t*)(p1 + t0 - 100);
            d2 = *(const uint32_t*)(p2 + t0 - 100); d3 = *(const uint32_t*)(p3 + t0 - 100);
        }
        uint32_t sw = 0;
        #pragma unroll
        for (int j = 0; j < 4; ++j) {
            int sh = 8 * j;
            int cnt  = (int)(((a0 >> sh) & 255u) + ((a1 >> sh) & 255u) +
                             ((a2 >> sh) & 255u) + ((a3 >> sh) & 255u));
            int cntd = (int)(((d0 >> sh) & 255u) + ((d1 >> sh) & 255u) +
                             ((d2 >> sh) & 255u) + ((d3 >> sh) & 255u));
            double x  = POOL_W * (double)cnt;
            double xd = POOL_W * (double)cntd;
            if (iir_step(c, st, x, xd)) sw |= 1u << sh;
        }
        *(uint32_t*)(sr + t0) = sw;
    }
    #pragma unroll
    for (int t0 = TREAL; t0 < TPAD; t0 += 4) *(uint32_t*)(sr + t0) = 0;
}

// ---------------------------------------------------------------------------
// Dense partials: grid (5, B, 16).  partial[p][b*10+o][t] f64 (validated r9).
// ---------------------------------------------------------------------------
__global__ __launch_bounds__(256) void dense_partial_kernel(
    const uint8_t* __restrict__ s5, const float* __restrict__ Wf,
    double* __restrict__ partial)
{
    const int tc = blockIdx.x, b = blockIdx.y, p = blockIdx.z;
    const int tid = threadIdx.x;
    const int tl = tid & 63, slot = tid >> 6;
    const int t = tc * 64 + tl;
    const int i0 = p * 256 + slot * 64;
    double acc[10];
    #pragma unroll
    for (int o = 0; o < 10; ++o) acc[o] = 0.0;
    const uint8_t* sp = s5 + ((size_t)b * 4096 + i0) * TPAD + t;
    for (int i = 0; i < 64; ++i) {
        float f = (float)sp[(size_t)i * TPAD];
        if (__any(f != 0.f)) {
            #pragma unroll
            for (int o = 0; o < 10; ++o)
                acc[o] = fma((double)Wf[o * 4096 + i0 + i], (double)f, acc[o]);
        }
    }
    __shared__ double red[4][64][10];
    #pragma unroll
    for (int o = 0; o < 10; ++o) red[slot][tl][o] = acc[o];
    __syncthreads();
    if (slot == 0) {
        #pragma unroll
        for (int o = 0; o < 10; ++o) {
            double v = ((red[0][tl][o] + red[1][tl][o]) + red[2][tl][o]) + red[3][tl][o];
            partial[((size_t)p * 160 + (size_t)b * 10 + o) * TPAD + t] = v;
        }
    }
}

// ---------------------------------------------------------------------------
// Final: one launch, block per (b,o) row (validated round 9).
// ---------------------------------------------------------------------------
__global__ __launch_bounds__(320) void psp_out_final_kernel(
    const double* __restrict__ partial, void* __restrict__ out,
    const int* __restrict__ flag)
{
    __shared__ double xs[TPAD];
    __shared__ uint8_t sb[TREAL];
    const int n = blockIdx.x;      // 0..159
    const int t = threadIdx.x;     // 0..319
    double v = 0.0;
    #pragma unroll
    for (int p = 0; p < 16; ++p)
        v += partial[((size_t)p * 160 + n) * TPAD + t];
    xs[t] = v;
    __syncthreads();
    if (t == 0) {
        const IIRC c = iirc_make();
        IIRS st; iirs_init(st);
        for (int i = 0; i < TREAL; ++i) {
            double xd = (i >= 100) ? xs[i - 100] : 0.0;
            sb[i] = iir_step(c, st, xs[i], xd) ? 1 : 0;
        }
    }
    __syncthreads();
    if (t < TREAL) {
        size_t e = (size_t)n * TREAL + t;
        if (*flag) ((uint16_t*)out)[e] = sb[t] ? 0x3F80 : 0;
        else       ((float*)out)[e]    = sb[t] ? 1.0f : 0.0f;
    }
}

// ---------------------------------------------------------------------------
__global__ __launch_bounds__(256) void fill_kernel(float* __restrict__ out, int n, float v)
{
    int i = blockIdx.x * 256 + threadIdx.x;
    if (i < n) out[i] = v;
}

// ---------------------------------------------------------------------------
static inline size_t alignup(size_t x) { return (x + 255) & ~(size_t)255; }

extern "C" void kernel_launch(void* const* d_in, const int* in_sizes, int n_in,
                              void* d_out, int out_size, void* d_ws, size_t ws_size,
                              hipStream_t stream)
{
    if (n_in != 5 || in_sizes[0] != 16 * 2 * 34 * 34 * 300 || in_sizes[1] != 800 ||
        in_sizes[2] != 4608 || in_sizes[3] != 18432 || in_sizes[4] != 40960 ||
        out_size != 16 * 10 * 300) {
        fill_kernel<<<(out_size + 255) / 256, 256, 0, stream>>>((float*)d_out, out_size, 2.0e5f);
        return;
    }

    const int NW[4] = {800, 4608, 18432, 40960};
    const size_t flag_sz  = alignup(sizeof(int));
    const size_t w64_sz   = alignup((size_t)(800 + 4608 + 18432) * 8);   // conv weights f64
    const size_t wf32_sz  = alignup((size_t)40960 * 4);                  // dense weights f32
    const size_t sin8_sz  = alignup((size_t)16 * 2 * 34 * 34 * TPAD);
    const size_t dpart_sz = alignup((size_t)16 * 160 * TPAD * 8);
    const size_t sA_sz    = alignup((size_t)16 * 16384 * TPAD);          // s1/s3/s5 slot
    const size_t sB_sz    = alignup((size_t)16 * 4096 * TPAD);           // s2/s4 slot
    const size_t need = flag_sz + w64_sz + wf32_sz + sin8_sz + dpart_sz + sA_sz + sB_sz;
    if (need > ws_size) {
        fill_kernel<<<(out_size + 255) / 256, 256, 0, stream>>>((float*)d_out, out_size, 1.0e5f);
        return;
    }

    char* base = (char*)d_ws;
    int* flag = (int*)base;          base += flag_sz;
    double* w64 = (double*)base;     base += w64_sz;
    float* wf32 = (float*)base;      base += wf32_sz;
    uint8_t* sin8 = (uint8_t*)base;  base += sin8_sz;
    double* dpart = (double*)base;   base += dpart_sz;
    uint8_t* sA = (uint8_t*)base;    base += sA_sz;
    uint8_t* sB = (uint8_t*)base;

    detect_kernel<<<1, 64, 0, stream>>>((const uint16_t*)d_in[1], flag);

    double* W64c[3];   // conv weights f64
    {
        size_t off = 0;
        for (int i = 0; i < 3; ++i) {
            W64c[i] = w64 + off;
            wcvt64_kernel<<<(NW[i] + 255) / 256, 256, 0, stream>>>(d_in[1 + i], W64c[i], NW[i], flag);
            off += NW[i];
        }
    }
    wcvt_kernel<<<(NW[3] + 255) / 256, 256, 0, stream>>>(d_in[4], wf32, NW[3], flag);
    convert_kernel<<<16 * 2 * 34 * 34, 320, 0, stream>>>(d_in[0], sin8, flag);

    // L1: conv 2->16, 5x5 pad1, 34->32 (+psp+scan fused)
    conv_psp_kernel<2, 5, 34><<<dim3(32 * 32, 1, 16), 320, 0, stream>>>(sin8, W64c[0], sA, 16);
    // L2: pool 32->16 (+psp+scan)
    pool_psp_iir_kernel<16, 32><<<(16 * 16 * 16 * 16 + 255) / 256, 256, 0, stream>>>(
        sA, sB, 16 * 16 * 16 * 16);
    // L3: conv 16->32, 3x3 pad1, 16->16
    conv_psp_kernel<16, 3, 16><<<dim3(16 * 16, 2, 16), 320, 0, stream>>>(sB, W64c[1], sA, 32);
    // L4: pool 16->8
    pool_psp_iir_kernel<32, 16><<<(16 * 32 * 8 * 8 + 255) / 256, 256, 0, stream>>>(
        sA, sB, 16 * 32 * 8 * 8);
    // L5: conv 32->64, 3x3 pad1, 8->8
    conv_psp_kernel<32, 3, 8><<<dim3(8 * 8, 4, 16), 320, 0, stream>>>(sB, W64c[2], sA, 64);
    // L6: dense partials + single final scan
    dense_partial_kernel<<<dim3(5, 16, 16), 256, 0, stream>>>(sA, wf32, dpart);
    psp_out_final_kernel<<<160, 320, 0, stream>>>(dpart, d_out, flag);
}

// Round 11
// 3799.463 us; speedup vs baseline: 1.1284x; 1.1284x over previous
//
#include <hip/hip_runtime.h>
#include <hip/hip_bf16.h>
#include <stdint.h>
#include <stddef.h>

#define TPAD 320   // padded time stride (300 real + 20 pad)
#define TREAL 300

// Python-f64 pool weight: float(1.1*10.0)  (validated exact, rounds 7-10)
#define POOL_W   11.000000000000002

static __device__ __forceinline__ float bf2f(uint16_t b) {
    return __uint_as_float(((uint32_t)b) << 16);
}

// ---------------------------------------------------------------------------
// f64 truncated-alpha IIR + refractory scan (validated exact, rounds 8-10).
// ---------------------------------------------------------------------------
struct IIRC { double DD, C1, C2, C3, DR; };
static __device__ __forceinline__ IIRC iirc_make() {
    IIRC c;
    c.DD = exp(-0.1);
    c.C1 = exp(1.0) / 10.0;
    c.C2 = exp(-9.0) / 10.0;
    c.C3 = 10.0 * exp(-9.0);
    c.DR = exp(-1.0);
    return c;
}
struct IIRS { double P, Q, P2, Q2, r; };
static __device__ __forceinline__ void iirs_init(IIRS& s) {
    s.P = 0.0; s.Q = 0.0; s.P2 = 0.0; s.Q2 = 0.0; s.r = 0.0;
}
static __device__ __forceinline__ bool iir_step(const IIRC& c, IIRS& st,
                                                double x, double xd) {
    double Qn  = c.DD * (st.Q + st.P);
    double Pn  = fma(c.DD, st.P, x);
    double Q2n = c.DD * (st.Q2 + st.P2);
    double P2n = fma(c.DD, st.P2, xd);
    double a = c.C1 * Qn - c.C2 * Q2n - c.C3 * P2n;
    double u = a + st.r;
    bool s = (u >= 10.0);
    st.r = c.DR * (st.r - (s ? 20.0 : 0.0));
    st.P = Pn; st.Q = Qn; st.P2 = P2n; st.Q2 = Q2n;
    return s;
}

// ---------------------------------------------------------------------------
__global__ void detect_kernel(const uint16_t* __restrict__ w1raw, int* __restrict__ flag)
{
    if (threadIdx.x == 0 && blockIdx.x == 0) {
        int sane = 1;
        for (int i = 0; i < 800; ++i) {
            int e = (w1raw[i] >> 7) & 0xFF;
            if (e >= 131) { sane = 0; break; }
        }
        *flag = sane;   // 1 = bf16, 0 = f32
    }
}

// Conv weights -> f64, transposed to [co_group][tap][16 co-in-group]:
// per tap the 16 co weights are 128 contiguous bytes -> one scalar-cache line.
__global__ __launch_bounds__(256) void wtrans_kernel(
    const void* __restrict__ w, double* __restrict__ out, int Co, int CKK,
    const int* __restrict__ flag)
{
    int i = blockIdx.x * 256 + threadIdx.x;
    if (i >= Co * CKK) return;
    int co = i / CKK, r = i - co * CKK;
    double v = (*flag) ? (double)bf2f(((const uint16_t*)w)[i])
                       : (double)((const float*)w)[i];
    out[(size_t)(co >> 4) * CKK * 16 + (size_t)r * 16 + (co & 15)] = v;
}

// Dense weights -> f32 (bf16->f32 exact)
__global__ __launch_bounds__(256) void wcvt_kernel(
    const void* __restrict__ w, float* __restrict__ out, int n, const int* __restrict__ flag)
{
    int i = blockIdx.x * 256 + threadIdx.x;
    if (i >= n) return;
    out[i] = (*flag) ? bf2f(((const uint16_t*)w)[i]) : ((const float*)w)[i];
}

__global__ __launch_bounds__(320) void convert_kernel(
    const void* __restrict__ s_in, uint8_t* __restrict__ u8, const int* __restrict__ flag)
{
    int row = blockIdx.x;
    int t = threadIdx.x;
    uint8_t v = 0;
    if (t < TREAL) {
        float x = (*flag) ? bf2f(((const uint16_t*)s_in)[(size_t)row * TREAL + t])
                          : ((const float*)s_in)[(size_t)row * TREAL + t];
        v = (x >= 0.5f) ? 1 : 0;
    }
    u8[(size_t)row * TPAD + t] = v;
}

// ---------------------------------------------------------------------------
// FUSED conv + PSP + scan, v2: LDS-staged inputs (round-10 failure was the
// per-tap load->__any round trip; here ALL taps are staged with one batched
// wait, then the FMA loop is straight-line).  Block = (pixel, 16-co, b),
// 320 t-lanes.  z lives only in LDS (union with the stage buffer).
// Grid: (Ho*Wo, Co_total/16, B)
// ---------------------------------------------------------------------------
template<int Ci, int CIB, int K, int Hi>
__global__ __launch_bounds__(320) void conv_psp_kernel(
    const uint8_t* __restrict__ sprev,   // [B][Ci][Hi][Wi][TPAD]
    const double* __restrict__ Wt,       // [Co/16][CKK][16] f64 (exact bf16)
    uint8_t* __restrict__ sout,          // [B][Co_total][Ho][Wo][TPAD]
    int Co_total)
{
    constexpr int P = 1;
    constexpr int Wi = Hi;
    constexpr int Ho = Hi + 2 * P - K + 1;
    constexpr int Wo = Ho;
    constexpr int KK = K * K;
    constexpr int CKK = Ci * KK;
    constexpr int SCKK = CIB * KK;          // taps per staging pass
    constexpr int NPASS = Ci / CIB;
    static_assert(Ci % CIB == 0, "pass split");

    constexpr int STAGE_B = SCKK * 320;                  // bytes
    constexpr int ZS_B    = 16 * 321 * 8 + 16 * 324;     // z + sb
    constexpr int SMEM_B  = (STAGE_B > ZS_B ? STAGE_B : ZS_B);
    __shared__ alignas(16) char smem[SMEM_B];
    static_assert(SMEM_B <= 60 * 1024, "LDS over limit");

    uint32_t* stage = (uint32_t*)smem;                   // [SCKK][80]
    double (*zl)[321] = (double(*)[321])smem;            // [16][321]
    uint8_t* sb = (uint8_t*)(smem + 16 * 321 * 8);       // [16][324]

    const int t   = threadIdx.x;             // 0..319
    const int h   = (int)blockIdx.x / Wo;
    const int w   = (int)blockIdx.x % Wo;
    const int gy  = (int)blockIdx.y;         // co group
    const int co0 = gy * 16;
    const int b   = (int)blockIdx.z;

    double acc[16];
    #pragma unroll
    for (int c = 0; c < 16; ++c) acc[c] = 0.0;

    const size_t in_b = (size_t)b * Ci * Hi * Wi * TPAD;
    const double* wg = Wt + (size_t)gy * CKK * 16;

    for (int p = 0; p < NPASS; ++p) {
        const int ci0 = p * CIB;
        __syncthreads();   // prior readers of stage done (and zl unused yet)
        for (int idx = t; idx < SCKK * 80; idx += 320) {
            int r  = idx / 80, dw = idx - r * 80;
            int cl = r / KK, rem = r - cl * KK;
            int ky = rem / K, kx = rem - ky * K;
            int row = h - P + ky;
            int col = w - P + kx;
            uint32_t v = 0;
            if ((unsigned)row < (unsigned)Hi && (unsigned)col < (unsigned)Wi)
                v = *(const uint32_t*)(sprev + in_b +
                      (((size_t)(ci0 + cl) * Hi + row) * Wi + col) * TPAD + dw * 4);
            stage[(size_t)r * 80 + dw] = v;
        }
        __syncthreads();

        const uint8_t* sbytes = (const uint8_t*)stage;
        #pragma unroll 4
        for (int r = 0; r < SCKK; ++r) {
            double x = (double)sbytes[(size_t)r * 320 + t];
            const double* wrow = wg + ((size_t)(p * SCKK + r)) * 16;  // uniform -> s_load
            #pragma unroll
            for (int c = 0; c < 16; ++c)
                acc[c] = fma(wrow[c], x, acc[c]);
        }
    }

    __syncthreads();   // stage reads done; smem becomes z/sb
    #pragma unroll
    for (int c = 0; c < 16; ++c) zl[c][t] = acc[c];
    #pragma unroll
    for (int c = 0; c < 16; ++c) sb[c * 324 + t] = 0;
    __syncthreads();

    if (t < 16) {      // lane t scans co = t
        const IIRC cc = iirc_make();
        IIRS st; iirs_init(st);
        #pragma unroll 4
        for (int i = 0; i < TREAL; ++i) {
            double xd = (i >= 100) ? zl[t][i - 100] : 0.0;
            sb[t * 324 + i] = iir_step(cc, st, zl[t][i], xd) ? 1 : 0;
        }
    }
    __syncthreads();

    #pragma unroll
    for (int c = 0; c < 16; ++c) {
        size_t off = ((((size_t)b * Co_total + co0 + c) * Ho + h) * Wo + w) * TPAD + t;
        sout[off] = sb[c * 324 + t];
    }
}

// ---------------------------------------------------------------------------
// Fused pool(2x2, w=POOL_W) + IIR-PSP + scan (validated rounds 8-10).
// ---------------------------------------------------------------------------
template<int C, int Hi>
__global__ __launch_bounds__(256) void pool_psp_iir_kernel(
    const uint8_t* __restrict__ sprev, uint8_t* __restrict__ sout, int N)
{
    constexpr int Wi = Hi, Ho = Hi / 2, Wo = Wi / 2;
    int n = blockIdx.x * 256 + threadIdx.x;
    if (n >= N) return;
    int wo = n % Wo;  int r1 = n / Wo;
    int ho = r1 % Ho; int r2 = r1 / Ho;
    int cc = r2 % C;  int b  = r2 / C;
    const uint8_t* p0 = sprev + ((((size_t)b * C + cc) * Hi + 2 * ho) * Wi + 2 * wo) * TPAD;
    const uint8_t* p1 = p0 + TPAD;
    const uint8_t* p2 = p0 + (size_t)Wi * TPAD;
    const uint8_t* p3 = p2 + TPAD;
    uint8_t* sr = sout + (size_t)n * TPAD;
    const IIRC c = iirc_make();
    IIRS st; iirs_init(st);
    for (int t0 = 0; t0 < TREAL; t0 += 4) {
        uint32_t a0 = *(const uint32_t*)(p0 + t0), a1 = *(const uint32_t*)(p1 + t0);
        uint32_t a2 = *(const uint32_t*)(p2 + t0), a3 = *(const uint32_t*)(p3 + t0);
        uint32_t d0 = 0, d1 = 0, d2 = 0, d3 = 0;
        if (t0 >= 100) {
            d0 = *(const uint32_t*)(p0 + t0 - 100); d1 = *(const uint32_t*)(p1 + t0 - 100);
            d2 = *(const uint32_t*)(p2 + t0 - 100); d3 = *(const uint32_t*)(p3 + t0 - 100);
        }
        uint32_t sw = 0;
        #pragma unroll
        for (int j = 0; j < 4; ++j) {
            int sh = 8 * j;
            int cnt  = (int)(((a0 >> sh) & 255u) + ((a1 >> sh) & 255u) +
                             ((a2 >> sh) & 255u) + ((a3 >> sh) & 255u));
            int cntd = (int)(((d0 >> sh) & 255u) + ((d1 >> sh) & 255u) +
                             ((d2 >> sh) & 255u) + ((d3 >> sh) & 255u));
            double x  = POOL_W * (double)cnt;
            double xd = POOL_W * (double)cntd;
            if (iir_step(c, st, x, xd)) sw |= 1u << sh;
        }
        *(uint32_t*)(sr + t0) = sw;
    }
    #pragma unroll
    for (int t0 = TREAL; t0 < TPAD; t0 += 4) *(uint32_t*)(sr + t0) = 0;
}

// ---------------------------------------------------------------------------
// Dense partials: grid (5, B, 16).  partial[p][b*10+o][t] f64 (validated r9).
// ---------------------------------------------------------------------------
__global__ __launch_bounds__(256) void dense_partial_kernel(
    const uint8_t* __restrict__ s5, const float* __restrict__ Wf,
    double* __restrict__ partial)
{
    const int tc = blockIdx.x, b = blockIdx.y, p = blockIdx.z;
    const int tid = threadIdx.x;
    const int tl = tid & 63, slot = tid >> 6;
    const int t = tc * 64 + tl;
    const int i0 = p * 256 + slot * 64;
    double acc[10];
    #pragma unroll
    for (int o = 0; o < 10; ++o) acc[o] = 0.0;
    const uint8_t* sp = s5 + ((size_t)b * 4096 + i0) * TPAD + t;
    for (int i = 0; i < 64; ++i) {
        float f = (float)sp[(size_t)i * TPAD];
        if (__any(f != 0.f)) {
            #pragma unroll
            for (int o = 0; o < 10; ++o)
                acc[o] = fma((double)Wf[o * 4096 + i0 + i], (double)f, acc[o]);
        }
    }
    __shared__ double red[4][64][10];
    #pragma unroll
    for (int o = 0; o < 10; ++o) red[slot][tl][o] = acc[o];
    __syncthreads();
    if (slot == 0) {
        #pragma unroll
        for (int o = 0; o < 10; ++o) {
            double v = ((red[0][tl][o] + red[1][tl][o]) + red[2][tl][o]) + red[3][tl][o];
            partial[((size_t)p * 160 + (size_t)b * 10 + o) * TPAD + t] = v;
        }
    }
}

// ---------------------------------------------------------------------------
// Final: one launch, block per (b,o) row (validated rounds 9/10).
// ---------------------------------------------------------------------------
__global__ __launch_bounds__(320) void psp_out_final_kernel(
    const double* __restrict__ partial, void* __restrict__ out,
    const int* __restrict__ flag)
{
    __shared__ double xs[TPAD];
    __shared__ uint8_t sb[TREAL];
    const int n = blockIdx.x;      // 0..159
    const int t = threadIdx.x;     // 0..319
    double v = 0.0;
    #pragma unroll
    for (int p = 0; p < 16; ++p)
        v += partial[((size_t)p * 160 + n) * TPAD + t];
    xs[t] = v;
    __syncthreads();
    if (t == 0) {
        const IIRC c = iirc_make();
        IIRS st; iirs_init(st);
        for (int i = 0; i < TREAL; ++i) {
            double xd = (i >= 100) ? xs[i - 100] : 0.0;
            sb[i] = iir_step(c, st, xs[i], xd) ? 1 : 0;
        }
    }
    __syncthreads();
    if (t < TREAL) {
        size_t e = (size_t)n * TREAL + t;
        if (*flag) ((uint16_t*)out)[e] = sb[t] ? 0x3F80 : 0;
        else       ((float*)out)[e]    = sb[t] ? 1.0f : 0.0f;
    }
}

// ---------------------------------------------------------------------------
__global__ __launch_bounds__(256) void fill_kernel(float* __restrict__ out, int n, float v)
{
    int i = blockIdx.x * 256 + threadIdx.x;
    if (i < n) out[i] = v;
}

// ---------------------------------------------------------------------------
static inline size_t alignup(size_t x) { return (x + 255) & ~(size_t)255; }

extern "C" void kernel_launch(void* const* d_in, const int* in_sizes, int n_in,
                              void* d_out, int out_size, void* d_ws, size_t ws_size,
                              hipStream_t stream)
{
    if (n_in != 5 || in_sizes[0] != 16 * 2 * 34 * 34 * 300 || in_sizes[1] != 800 ||
        in_sizes[2] != 4608 || in_sizes[3] != 18432 || in_sizes[4] != 40960 ||
        out_size != 16 * 10 * 300) {
        fill_kernel<<<(out_size + 255) / 256, 256, 0, stream>>>((float*)d_out, out_size, 2.0e5f);
        return;
    }

    const size_t flag_sz  = alignup(sizeof(int));
    const size_t w64_sz   = alignup((size_t)(800 + 4608 + 18432) * 8);   // conv wt f64
    const size_t wf32_sz  = alignup((size_t)40960 * 4);
    const size_t sin8_sz  = alignup((size_t)16 * 2 * 34 * 34 * TPAD);
    const size_t dpart_sz = alignup((size_t)16 * 160 * TPAD * 8);
    const size_t sA_sz    = alignup((size_t)16 * 16384 * TPAD);          // s1/s3/s5
    const size_t sB_sz    = alignup((size_t)16 * 4096 * TPAD);           // s2/s4
    const size_t need = flag_sz + w64_sz + wf32_sz + sin8_sz + dpart_sz + sA_sz + sB_sz;
    if (need > ws_size) {
        fill_kernel<<<(out_size + 255) / 256, 256, 0, stream>>>((float*)d_out, out_size, 1.0e5f);
        return;
    }

    char* base = (char*)d_ws;
    int* flag = (int*)base;          base += flag_sz;
    double* w64 = (double*)base;     base += w64_sz;
    float* wf32 = (float*)base;      base += wf32_sz;
    uint8_t* sin8 = (uint8_t*)base;  base += sin8_sz;
    double* dpart = (double*)base;   base += dpart_sz;
    uint8_t* sA = (uint8_t*)base;    base += sA_sz;
    uint8_t* sB = (uint8_t*)base;

    detect_kernel<<<1, 64, 0, stream>>>((const uint16_t*)d_in[1], flag);

    double* Wt1 = w64;                 // [1][50][16]
    double* Wt2 = w64 + 800;           // [2][144][16]
    double* Wt3 = w64 + 800 + 4608;    // [4][288][16]
    wtrans_kernel<<<(800 + 255) / 256, 256, 0, stream>>>(d_in[1], Wt1, 16, 50, flag);
    wtrans_kernel<<<(4608 + 255) / 256, 256, 0, stream>>>(d_in[2], Wt2, 32, 144, flag);
    wtrans_kernel<<<(18432 + 255) / 256, 256, 0, stream>>>(d_in[3], Wt3, 64, 288, flag);
    wcvt_kernel<<<(40960 + 255) / 256, 256, 0, stream>>>(d_in[4], wf32, 40960, flag);
    convert_kernel<<<16 * 2 * 34 * 34, 320, 0, stream>>>(d_in[0], sin8, flag);

    // L1: conv 2->16, 5x5 pad1, 34->32 (+psp+scan fused, z in LDS)
    conv_psp_kernel<2, 2, 5, 34><<<dim3(32 * 32, 1, 16), 320, 0, stream>>>(sin8, Wt1, sA, 16);
    // L2: pool 32->16 (+psp+scan)
    pool_psp_iir_kernel<16, 32><<<(16 * 16 * 16 * 16 + 255) / 256, 256, 0, stream>>>(
        sA, sB, 16 * 16 * 16 * 16);
    // L3: conv 16->32, 3x3 pad1, 16->16
    conv_psp_kernel<16, 16, 3, 16><<<dim3(16 * 16, 2, 16), 320, 0, stream>>>(sB, Wt2, sA, 32);
    // L4: pool 16->8
    pool_psp_iir_kernel<32, 16><<<(16 * 32 * 8 * 8 + 255) / 256, 256, 0, stream>>>(
        sA, sB, 16 * 32 * 8 * 8);
    // L5: conv 32->64, 3x3 pad1, 8->8 (two 16-ci staging passes)
    conv_psp_kernel<32, 16, 3, 8><<<dim3(8 * 8, 4, 16), 320, 0, stream>>>(sB, Wt3, sA, 64);
    // L6: dense partials + single final scan
    dense_partial_kernel<<<dim3(5, 16, 16), 256, 0, stream>>>(sA, wf32, dpart);
    psp_out_final_kernel<<<160, 320, 0, stream>>>(dpart, d_out, flag);
}

// Round 12
// 3104.008 us; speedup vs baseline: 1.3812x; 1.2241x over previous
//
#include <hip/hip_runtime.h>
#include <hip/hip_bf16.h>
#include <stdint.h>
#include <stddef.h>

#define TPAD 320   // padded time stride (300 real + 20 pad)
#define TREAL 300

// Python-f64 pool weight: float(1.1*10.0)  (validated exact, rounds 7-11)
#define POOL_W   11.000000000000002

static __device__ __forceinline__ float bf2f(uint16_t b) {
    return __uint_as_float(((uint32_t)b) << 16);
}

// ---------------------------------------------------------------------------
// f64 truncated-alpha IIR + refractory scan (validated exact, rounds 8-11).
// ---------------------------------------------------------------------------
struct IIRC { double DD, C1, C2, C3, DR; };
static __device__ __forceinline__ IIRC iirc_make() {
    IIRC c;
    c.DD = exp(-0.1);
    c.C1 = exp(1.0) / 10.0;
    c.C2 = exp(-9.0) / 10.0;
    c.C3 = 10.0 * exp(-9.0);
    c.DR = exp(-1.0);
    return c;
}
struct IIRS { double P, Q, P2, Q2, r; };
static __device__ __forceinline__ void iirs_init(IIRS& s) {
    s.P = 0.0; s.Q = 0.0; s.P2 = 0.0; s.Q2 = 0.0; s.r = 0.0;
}
static __device__ __forceinline__ bool iir_step(const IIRC& c, IIRS& st,
                                                double x, double xd) {
    double Qn  = c.DD * (st.Q + st.P);
    double Pn  = fma(c.DD, st.P, x);
    double Q2n = c.DD * (st.Q2 + st.P2);
    double P2n = fma(c.DD, st.P2, xd);
    double a = c.C1 * Qn - c.C2 * Q2n - c.C3 * P2n;
    double u = a + st.r;
    bool s = (u >= 10.0);
    st.r = c.DR * (st.r - (s ? 20.0 : 0.0));
    st.P = Pn; st.Q = Qn; st.P2 = P2n; st.Q2 = Q2n;
    return s;
}

// ---------------------------------------------------------------------------
__global__ void detect_kernel(const uint16_t* __restrict__ w1raw, int* __restrict__ flag)
{
    if (threadIdx.x == 0 && blockIdx.x == 0) {
        int sane = 1;
        for (int i = 0; i < 800; ++i) {
            int e = (w1raw[i] >> 7) & 0xFF;
            if (e >= 131) { sane = 0; break; }
        }
        *flag = sane;   // 1 = bf16, 0 = f32
    }
}

// Conv weights -> f64, transposed to [co_group][tap][16 co-in-group].
__global__ __launch_bounds__(256) void wtrans_kernel(
    const void* __restrict__ w, double* __restrict__ out, int Co, int CKK,
    const int* __restrict__ flag)
{
    int i = blockIdx.x * 256 + threadIdx.x;
    if (i >= Co * CKK) return;
    int co = i / CKK, r = i - co * CKK;
    double v = (*flag) ? (double)bf2f(((const uint16_t*)w)[i])
                       : (double)((const float*)w)[i];
    out[(size_t)(co >> 4) * CKK * 16 + (size_t)r * 16 + (co & 15)] = v;
}

// Dense weights -> f32 (bf16->f32 exact)
__global__ __launch_bounds__(256) void wcvt_kernel(
    const void* __restrict__ w, float* __restrict__ out, int n, const int* __restrict__ flag)
{
    int i = blockIdx.x * 256 + threadIdx.x;
    if (i >= n) return;
    out[i] = (*flag) ? bf2f(((const uint16_t*)w)[i]) : ((const float*)w)[i];
}

__global__ __launch_bounds__(320) void convert_kernel(
    const void* __restrict__ s_in, uint8_t* __restrict__ u8, const int* __restrict__ flag)
{
    int row = blockIdx.x;
    int t = threadIdx.x;
    uint8_t v = 0;
    if (t < TREAL) {
        float x = (*flag) ? bf2f(((const uint16_t*)s_in)[(size_t)row * TREAL + t])
                          : ((const float*)s_in)[(size_t)row * TREAL + t];
        v = (x >= 0.5f) ? 1 : 0;
    }
    u8[(size_t)row * TPAD + t] = v;
}

// ---------------------------------------------------------------------------
// Conv -> z (f64, global).  Round-11's staged-FMA structure (validated) with
// the fused scan removed: LDS = stage only, z written coalesced.
// Block = (pixel, 16-co group, b_in_chunk), 320 t-lanes.
// Grid: (Ho*Wo, Co_total/16, Bg)
// ---------------------------------------------------------------------------
template<int Ci, int CIB, int K, int Hi>
__global__ __launch_bounds__(320) void conv_z_kernel(
    const uint8_t* __restrict__ sprev,   // chunk-local [Bg][Ci][Hi][Wi][TPAD]
    const double* __restrict__ Wt,       // [Co/16][CKK][16] f64 (exact bf16)
    double* __restrict__ z,              // chunk-local [Bg][Co][Ho][Wo][TPAD]
    int Co_total)
{
    constexpr int P = 1;
    constexpr int Wi = Hi;
    constexpr int Ho = Hi + 2 * P - K + 1;
    constexpr int Wo = Ho;
    constexpr int KK = K * K;
    constexpr int CKK = Ci * KK;
    constexpr int SCKK = CIB * KK;
    constexpr int NPASS = Ci / CIB;
    static_assert(Ci % CIB == 0, "pass split");
    static_assert(SCKK * 320 <= 60 * 1024, "LDS over limit");

    __shared__ uint32_t stage[SCKK * 80];

    const int t   = threadIdx.x;             // 0..319
    const int h   = (int)blockIdx.x / Wo;
    const int w   = (int)blockIdx.x % Wo;
    const int gy  = (int)blockIdx.y;
    const int co0 = gy * 16;
    const int b   = (int)blockIdx.z;

    double acc[16];
    #pragma unroll
    for (int c = 0; c < 16; ++c) acc[c] = 0.0;

    const size_t in_b = (size_t)b * Ci * Hi * Wi * TPAD;
    const double* wg = Wt + (size_t)gy * CKK * 16;

    for (int p = 0; p < NPASS; ++p) {
        const int ci0 = p * CIB;
        __syncthreads();
        for (int idx = t; idx < SCKK * 80; idx += 320) {
            int r  = idx / 80, dw = idx - r * 80;
            int cl = r / KK, rem = r - cl * KK;
            int ky = rem / K, kx = rem - ky * K;
            int row = h - P + ky;
            int col = w - P + kx;
            uint32_t v = 0;
            if ((unsigned)row < (unsigned)Hi && (unsigned)col < (unsigned)Wi)
                v = *(const uint32_t*)(sprev + in_b +
                      (((size_t)(ci0 + cl) * Hi + row) * Wi + col) * TPAD + dw * 4);
            stage[(size_t)r * 80 + dw] = v;
        }
        __syncthreads();

        const uint8_t* sbytes = (const uint8_t*)stage;
        #pragma unroll 4
        for (int r = 0; r < SCKK; ++r) {
            double x = (double)sbytes[(size_t)r * 320 + t];
            const double* wrow = wg + ((size_t)(p * SCKK + r)) * 16;  // uniform -> s_load
            #pragma unroll
            for (int c = 0; c < 16; ++c)
                acc[c] = fma(wrow[c], x, acc[c]);
        }
    }

    #pragma unroll
    for (int c = 0; c < 16; ++c) {
        size_t row = (((size_t)b * Co_total + co0 + c) * Ho + h) * Wo + w;
        z[row * TPAD + t] = acc[c];
    }
}

// ---------------------------------------------------------------------------
// PSP + scan over z.  Lane = row.  t-loop SPLIT at t=100 (branch-free bodies
// -> unroll + prefetch; round-9's in-loop branch was the latency serializer).
// xd reads hit L1/L2 (same row, 800 B behind the x stream).
// ---------------------------------------------------------------------------
__global__ __launch_bounds__(256) void psp_scan_kernel(
    const double* __restrict__ z, uint8_t* __restrict__ sout, int N)
{
    int n = blockIdx.x * 256 + threadIdx.x;
    if (n >= N) return;
    const double* zr = z + (size_t)n * TPAD;
    uint8_t* sr = sout + (size_t)n * TPAD;
    const IIRC c = iirc_make();
    IIRS st; iirs_init(st);
    #pragma unroll 5
    for (int t0 = 0; t0 < 100; t0 += 4) {
        double2 xa = *(const double2*)(zr + t0);
        double2 xb = *(const double2*)(zr + t0 + 2);
        uint32_t sw = 0;
        if (iir_step(c, st, xa.x, 0.0)) sw |= 1u;
        if (iir_step(c, st, xa.y, 0.0)) sw |= 1u << 8;
        if (iir_step(c, st, xb.x, 0.0)) sw |= 1u << 16;
        if (iir_step(c, st, xb.y, 0.0)) sw |= 1u << 24;
        *(uint32_t*)(sr + t0) = sw;
    }
    #pragma unroll 5
    for (int t0 = 100; t0 < TREAL; t0 += 4) {
        double2 xa = *(const double2*)(zr + t0);
        double2 xb = *(const double2*)(zr + t0 + 2);
        double2 da = *(const double2*)(zr + t0 - 100);
        double2 db = *(const double2*)(zr + t0 - 98);
        uint32_t sw = 0;
        if (iir_step(c, st, xa.x, da.x)) sw |= 1u;
        if (iir_step(c, st, xa.y, da.y)) sw |= 1u << 8;
        if (iir_step(c, st, xb.x, db.x)) sw |= 1u << 16;
        if (iir_step(c, st, xb.y, db.y)) sw |= 1u << 24;
        *(uint32_t*)(sr + t0) = sw;
    }
    #pragma unroll
    for (int t0 = TREAL; t0 < TPAD; t0 += 4) *(uint32_t*)(sr + t0) = 0;
}

// ---------------------------------------------------------------------------
// Fused pool(2x2, w=POOL_W) + IIR-PSP + scan (validated rounds 8-11).
// ---------------------------------------------------------------------------
template<int C, int Hi>
__global__ __launch_bounds__(256) void pool_psp_iir_kernel(
    const uint8_t* __restrict__ sprev, uint8_t* __restrict__ sout, int N)
{
    constexpr int Wi = Hi, Ho = Hi / 2, Wo = Wi / 2;
    int n = blockIdx.x * 256 + threadIdx.x;
    if (n >= N) return;
    int wo = n % Wo;  int r1 = n / Wo;
    int ho = r1 % Ho; int r2 = r1 / Ho;
    int cc = r2 % C;  int b  = r2 / C;
    const uint8_t* p0 = sprev + ((((size_t)b * C + cc) * Hi + 2 * ho) * Wi + 2 * wo) * TPAD;
    const uint8_t* p1 = p0 + TPAD;
    const uint8_t* p2 = p0 + (size_t)Wi * TPAD;
    const uint8_t* p3 = p2 + TPAD;
    uint8_t* sr = sout + (size_t)n * TPAD;
    const IIRC c = iirc_make();
    IIRS st; iirs_init(st);
    for (int t0 = 0; t0 < TREAL; t0 += 4) {
        uint32_t a0 = *(const uint32_t*)(p0 + t0), a1 = *(const uint32_t*)(p1 + t0);
        uint32_t a2 = *(const uint32_t*)(p2 + t0), a3 = *(const uint32_t*)(p3 + t0);
        uint32_t d0 = 0, d1 = 0, d2 = 0, d3 = 0;
        if (t0 >= 100) {
            d0 = *(const uint32_t*)(p0 + t0 - 100); d1 = *(const uint32_t*)(p1 + t0 - 100);
            d2 = *(const uint32_t*)(p2 + t0 - 100); d3 = *(const uint32_t*)(p3 + t0 - 100);
        }
        uint32_t sw = 0;
        #pragma unroll
        for (int j = 0; j < 4; ++j) {
            int sh = 8 * j;
            int cnt  = (int)(((a0 >> sh) & 255u) + ((a1 >> sh) & 255u) +
                             ((a2 >> sh) & 255u) + ((a3 >> sh) & 255u));
            int cntd = (int)(((d0 >> sh) & 255u) + ((d1 >> sh) & 255u) +
                             ((d2 >> sh) & 255u) + ((d3 >> sh) & 255u));
            double x  = POOL_W * (double)cnt;
            double xd = POOL_W * (double)cntd;
            if (iir_step(c, st, x, xd)) sw |= 1u << sh;
        }
        *(uint32_t*)(sr + t0) = sw;
    }
    #pragma unroll
    for (int t0 = TREAL; t0 < TPAD; t0 += 4) *(uint32_t*)(sr + t0) = 0;
}

// ---------------------------------------------------------------------------
// Dense partials: grid (5, B, 16).  partial[p][b*10+o][t] f64 (validated r9+).
// ---------------------------------------------------------------------------
__global__ __launch_bounds__(256) void dense_partial_kernel(
    const uint8_t* __restrict__ s5, const float* __restrict__ Wf,
    double* __restrict__ partial)
{
    const int tc = blockIdx.x, b = blockIdx.y, p = blockIdx.z;
    const int tid = threadIdx.x;
    const int tl = tid & 63, slot = tid >> 6;
    const int t = tc * 64 + tl;
    const int i0 = p * 256 + slot * 64;
    double acc[10];
    #pragma unroll
    for (int o = 0; o < 10; ++o) acc[o] = 0.0;
    const uint8_t* sp = s5 + ((size_t)b * 4096 + i0) * TPAD + t;
    for (int i = 0; i < 64; ++i) {
        float f = (float)sp[(size_t)i * TPAD];
        if (__any(f != 0.f)) {
            #pragma unroll
            for (int o = 0; o < 10; ++o)
                acc[o] = fma((double)Wf[o * 4096 + i0 + i], (double)f, acc[o]);
        }
    }
    __shared__ double red[4][64][10];
    #pragma unroll
    for (int o = 0; o < 10; ++o) red[slot][tl][o] = acc[o];
    __syncthreads();
    if (slot == 0) {
        #pragma unroll
        for (int o = 0; o < 10; ++o) {
            double v = ((red[0][tl][o] + red[1][tl][o]) + red[2][tl][o]) + red[3][tl][o];
            partial[((size_t)p * 160 + (size_t)b * 10 + o) * TPAD + t] = v;
        }
    }
}

// ---------------------------------------------------------------------------
// Final: one launch, block per (b,o) row (validated rounds 9-11).
// ---------------------------------------------------------------------------
__global__ __launch_bounds__(320) void psp_out_final_kernel(
    const double* __restrict__ partial, void* __restrict__ out,
    const int* __restrict__ flag)
{
    __shared__ double xs[TPAD];
    __shared__ uint8_t sb[TREAL];
    const int n = blockIdx.x;      // 0..159
    const int t = threadIdx.x;     // 0..319
    double v = 0.0;
    #pragma unroll
    for (int p = 0; p < 16; ++p)
        v += partial[((size_t)p * 160 + n) * TPAD + t];
    xs[t] = v;
    __syncthreads();
    if (t == 0) {
        const IIRC c = iirc_make();
        IIRS st; iirs_init(st);
        for (int i = 0; i < TREAL; ++i) {
            double xd = (i >= 100) ? xs[i - 100] : 0.0;
            sb[i] = iir_step(c, st, xs[i], xd) ? 1 : 0;
        }
    }
    __syncthreads();
    if (t < TREAL) {
        size_t e = (size_t)n * TREAL + t;
        if (*flag) ((uint16_t*)out)[e] = sb[t] ? 0x3F80 : 0;
        else       ((float*)out)[e]    = sb[t] ? 1.0f : 0.0f;
    }
}

// ---------------------------------------------------------------------------
__global__ __launch_bounds__(256) void fill_kernel(float* __restrict__ out, int n, float v)
{
    int i = blockIdx.x * 256 + threadIdx.x;
    if (i < n) out[i] = v;
}

// ---------------------------------------------------------------------------
static inline size_t alignup(size_t x) { return (x + 255) & ~(size_t)255; }
static inline int pick_bg(size_t per_b, size_t budget) {
    const int cand[5] = {16, 8, 4, 2, 1};
    for (int k = 0; k < 5; ++k)
        if (per_b * (size_t)cand[k] <= budget) return cand[k];
    return 0;
}

extern "C" void kernel_launch(void* const* d_in, const int* in_sizes, int n_in,
                              void* d_out, int out_size, void* d_ws, size_t ws_size,
                              hipStream_t stream)
{
    if (n_in != 5 || in_sizes[0] != 16 * 2 * 34 * 34 * 300 || in_sizes[1] != 800 ||
        in_sizes[2] != 4608 || in_sizes[3] != 18432 || in_sizes[4] != 40960 ||
        out_size != 16 * 10 * 300) {
        fill_kernel<<<(out_size + 255) / 256, 256, 0, stream>>>((float*)d_out, out_size, 2.0e5f);
        return;
    }

    const size_t flag_sz  = alignup(sizeof(int));
    const size_t w64_sz   = alignup((size_t)(800 + 4608 + 18432) * 8);
    const size_t wf32_sz  = alignup((size_t)40960 * 4);
    const size_t sin8_sz  = alignup((size_t)16 * 2 * 34 * 34 * TPAD);
    const size_t dpart_sz = alignup((size_t)16 * 160 * TPAD * 8);
    const size_t sA_sz    = alignup((size_t)16 * 16384 * TPAD);   // s1/s3/s5 (full batch)
    const size_t sB_sz    = alignup((size_t)16 * 4096 * TPAD);    // s2/s4   (full batch)
    const size_t base_sz  = flag_sz + w64_sz + wf32_sz + sin8_sz + dpart_sz + sA_sz + sB_sz;
    if (base_sz + 256 > ws_size) {
        fill_kernel<<<(out_size + 255) / 256, 256, 0, stream>>>((float*)d_out, out_size, 1.0e5f);
        return;
    }
    const size_t zbud = ws_size - base_sz - 256;

    // per-batch z sizes (f64): L1 16x32x32, L3 32x16x16, L5 64x8x8 rows x TPAD
    const size_t zb1 = (size_t)16 * 1024 * TPAD * 8;   // 41.9 MB
    const size_t zb3 = (size_t)32 * 256 * TPAD * 8;    // 21.0 MB
    const size_t zb5 = (size_t)64 * 64 * TPAD * 8;     // 10.5 MB
    const int bg1 = pick_bg(zb1, zbud), bg3 = pick_bg(zb3, zbud), bg5 = pick_bg(zb5, zbud);
    if (bg1 == 0 || bg3 == 0 || bg5 == 0) {
        fill_kernel<<<(out_size + 255) / 256, 256, 0, stream>>>((float*)d_out, out_size, 1.0e5f);
        return;
    }

    char* base = (char*)d_ws;
    int* flag = (int*)base;          base += flag_sz;
    double* w64 = (double*)base;     base += w64_sz;
    float* wf32 = (float*)base;      base += wf32_sz;
    uint8_t* sin8 = (uint8_t*)base;  base += sin8_sz;
    double* dpart = (double*)base;   base += dpart_sz;
    uint8_t* sA = (uint8_t*)base;    base += sA_sz;
    uint8_t* sB = (uint8_t*)base;    base += sB_sz;
    double* z64 = (double*)base;

    detect_kernel<<<1, 64, 0, stream>>>((const uint16_t*)d_in[1], flag);

    double* Wt1 = w64;                 // [1][50][16]
    double* Wt2 = w64 + 800;           // [2][144][16]
    double* Wt3 = w64 + 800 + 4608;    // [4][288][16]
    wtrans_kernel<<<(800 + 255) / 256, 256, 0, stream>>>(d_in[1], Wt1, 16, 50, flag);
    wtrans_kernel<<<(4608 + 255) / 256, 256, 0, stream>>>(d_in[2], Wt2, 32, 144, flag);
    wtrans_kernel<<<(18432 + 255) / 256, 256, 0, stream>>>(d_in[3], Wt3, 64, 288, flag);
    wcvt_kernel<<<(40960 + 255) / 256, 256, 0, stream>>>(d_in[4], wf32, 40960, flag);
    convert_kernel<<<16 * 2 * 34 * 34, 320, 0, stream>>>(d_in[0], sin8, flag);

    // L1: conv 2->16, 5x5 pad1, 34->32 (z-chunked) + psp scan
    for (int b0 = 0; b0 < 16; b0 += bg1) {
        conv_z_kernel<2, 2, 5, 34><<<dim3(1024, 1, bg1), 320, 0, stream>>>(
            sin8 + (size_t)b0 * 2 * 34 * 34 * TPAD, Wt1, z64, 16);
        int N = bg1 * 16384;
        psp_scan_kernel<<<(N + 255) / 256, 256, 0, stream>>>(
            z64, sA + (size_t)b0 * 16384 * TPAD, N);
    }
    // L2: pool 32->16 (+psp+scan), full batch
    pool_psp_iir_kernel<16, 32><<<(16 * 4096 + 255) / 256, 256, 0, stream>>>(
        sA, sB, 16 * 4096);
    // L3: conv 16->32, 3x3 pad1, 16->16
    for (int b0 = 0; b0 < 16; b0 += bg3) {
        conv_z_kernel<16, 16, 3, 16><<<dim3(256, 2, bg3), 320, 0, stream>>>(
            sB + (size_t)b0 * 16 * 256 * TPAD, Wt2, z64, 32);
        int N = bg3 * 8192;
        psp_scan_kernel<<<(N + 255) / 256, 256, 0, stream>>>(
            z64, sA + (size_t)b0 * 8192 * TPAD, N);
    }
    // L4: pool 16->8, full batch
    pool_psp_iir_kernel<32, 16><<<(16 * 2048 + 255) / 256, 256, 0, stream>>>(
        sA, sB, 16 * 2048);
    // L5: conv 32->64, 3x3 pad1, 8->8 (two 16-ci staging passes)
    for (int b0 = 0; b0 < 16; b0 += bg5) {
        conv_z_kernel<32, 16, 3, 8><<<dim3(64, 4, bg5), 320, 0, stream>>>(
            sB + (size_t)b0 * 32 * 64 * TPAD, Wt3, z64, 64);
        int N = bg5 * 4096;
        psp_scan_kernel<<<(N + 255) / 256, 256, 0, stream>>>(
            z64, sA + (size_t)b0 * 4096 * TPAD, N);
    }
    // L6: dense partials + single final scan
    dense_partial_kernel<<<dim3(5, 16, 16), 256, 0, stream>>>(sA, wf32, dpart);
    psp_out_final_kernel<<<160, 320, 0, stream>>>(dpart, d_out, flag);
}

// Round 13
// 2467.724 us; speedup vs baseline: 1.7373x; 1.2578x over previous
//
#include <hip/hip_runtime.h>
#include <hip/hip_bf16.h>
#include <stdint.h>
#include <stddef.h>

#define TPAD 320   // padded time stride (300 real + 20 pad)
#define TREAL 300

// Python-f64 pool weight: float(1.1*10.0)  (validated exact, rounds 7-12)
#define POOL_W   11.000000000000002

static __device__ __forceinline__ float bf2f(uint16_t b) {
    return __uint_as_float(((uint32_t)b) << 16);
}

// ---------------------------------------------------------------------------
// f64 truncated-alpha IIR + refractory scan (validated exact, rounds 8-12).
// ---------------------------------------------------------------------------
struct IIRC { double DD, C1, C2, C3, DR; };
static __device__ __forceinline__ IIRC iirc_make() {
    IIRC c;
    c.DD = exp(-0.1);
    c.C1 = exp(1.0) / 10.0;
    c.C2 = exp(-9.0) / 10.0;
    c.C3 = 10.0 * exp(-9.0);
    c.DR = exp(-1.0);
    return c;
}
struct IIRS { double P, Q, P2, Q2, r; };
static __device__ __forceinline__ void iirs_init(IIRS& s) {
    s.P = 0.0; s.Q = 0.0; s.P2 = 0.0; s.Q2 = 0.0; s.r = 0.0;
}
static __device__ __forceinline__ bool iir_step(const IIRC& c, IIRS& st,
                                                double x, double xd) {
    double Qn  = c.DD * (st.Q + st.P);
    double Pn  = fma(c.DD, st.P, x);
    double Q2n = c.DD * (st.Q2 + st.P2);
    double P2n = fma(c.DD, st.P2, xd);
    double a = c.C1 * Qn - c.C2 * Q2n - c.C3 * P2n;
    double u = a + st.r;
    bool s = (u >= 10.0);
    st.r = c.DR * (st.r - (s ? 20.0 : 0.0));
    st.P = Pn; st.Q = Qn; st.P2 = P2n; st.Q2 = Q2n;
    return s;
}

// ---------------------------------------------------------------------------
__global__ void detect_kernel(const uint16_t* __restrict__ w1raw, int* __restrict__ flag)
{
    if (threadIdx.x == 0 && blockIdx.x == 0) {
        int sane = 1;
        for (int i = 0; i < 800; ++i) {
            int e = (w1raw[i] >> 7) & 0xFF;
            if (e >= 131) { sane = 0; break; }
        }
        *flag = sane;   // 1 = bf16, 0 = f32
    }
}

// Conv weights -> f64, transposed to [co_group][tap][16 co-in-group].
__global__ __launch_bounds__(256) void wtrans_kernel(
    const void* __restrict__ w, double* __restrict__ out, int Co, int CKK,
    const int* __restrict__ flag)
{
    int i = blockIdx.x * 256 + threadIdx.x;
    if (i >= Co * CKK) return;
    int co = i / CKK, r = i - co * CKK;
    double v = (*flag) ? (double)bf2f(((const uint16_t*)w)[i])
                       : (double)((const float*)w)[i];
    out[(size_t)(co >> 4) * CKK * 16 + (size_t)r * 16 + (co & 15)] = v;
}

// Dense weights -> f32 (bf16->f32 exact)
__global__ __launch_bounds__(256) void wcvt_kernel(
    const void* __restrict__ w, float* __restrict__ out, int n, const int* __restrict__ flag)
{
    int i = blockIdx.x * 256 + threadIdx.x;
    if (i >= n) return;
    out[i] = (*flag) ? bf2f(((const uint16_t*)w)[i]) : ((const float*)w)[i];
}

__global__ __launch_bounds__(320) void convert_kernel(
    const void* __restrict__ s_in, uint8_t* __restrict__ u8, const int* __restrict__ flag)
{
    int row = blockIdx.x;
    int t = threadIdx.x;
    uint8_t v = 0;
    if (t < TREAL) {
        float x = (*flag) ? bf2f(((const uint16_t*)s_in)[(size_t)row * TREAL + t])
                          : ((const float*)s_in)[(size_t)row * TREAL + t];
        v = (x >= 0.5f) ? 1 : 0;
    }
    u8[(size_t)row * TPAD + t] = v;
}

// ---------------------------------------------------------------------------
// Conv -> z (f64, global).  Validated structure (rounds 11/12).
// Grid: (Ho*Wo, Co_total/16, Bg)
// ---------------------------------------------------------------------------
template<int Ci, int CIB, int K, int Hi>
__global__ __launch_bounds__(320) void conv_z_kernel(
    const uint8_t* __restrict__ sprev,   // chunk-local [Bg][Ci][Hi][Wi][TPAD]
    const double* __restrict__ Wt,       // [Co/16][CKK][16] f64 (exact bf16)
    double* __restrict__ z,              // chunk-local [Bg][Co][Ho][Wo][TPAD]
    int Co_total)
{
    constexpr int P = 1;
    constexpr int Wi = Hi;
    constexpr int Ho = Hi + 2 * P - K + 1;
    constexpr int Wo = Ho;
    constexpr int KK = K * K;
    constexpr int CKK = Ci * KK;
    constexpr int SCKK = CIB * KK;
    constexpr int NPASS = Ci / CIB;
    static_assert(Ci % CIB == 0, "pass split");
    static_assert(SCKK * 320 <= 60 * 1024, "LDS over limit");

    __shared__ uint32_t stage[SCKK * 80];

    const int t   = threadIdx.x;             // 0..319
    const int h   = (int)blockIdx.x / Wo;
    const int w   = (int)blockIdx.x % Wo;
    const int gy  = (int)blockIdx.y;
    const int co0 = gy * 16;
    const int b   = (int)blockIdx.z;

    double acc[16];
    #pragma unroll
    for (int c = 0; c < 16; ++c) acc[c] = 0.0;

    const size_t in_b = (size_t)b * Ci * Hi * Wi * TPAD;
    const double* wg = Wt + (size_t)gy * CKK * 16;

    for (int p = 0; p < NPASS; ++p) {
        const int ci0 = p * CIB;
        __syncthreads();
        for (int idx = t; idx < SCKK * 80; idx += 320) {
            int r  = idx / 80, dw = idx - r * 80;
            int cl = r / KK, rem = r - cl * KK;
            int ky = rem / K, kx = rem - ky * K;
            int row = h - P + ky;
            int col = w - P + kx;
            uint32_t v = 0;
            if ((unsigned)row < (unsigned)Hi && (unsigned)col < (unsigned)Wi)
                v = *(const uint32_t*)(sprev + in_b +
                      (((size_t)(ci0 + cl) * Hi + row) * Wi + col) * TPAD + dw * 4);
            stage[(size_t)r * 80 + dw] = v;
        }
        __syncthreads();

        const uint8_t* sbytes = (const uint8_t*)stage;
        #pragma unroll 4
        for (int r = 0; r < SCKK; ++r) {
            double x = (double)sbytes[(size_t)r * 320 + t];
            const double* wrow = wg + ((size_t)(p * SCKK + r)) * 16;  // uniform -> s_load
            #pragma unroll
            for (int c = 0; c < 16; ++c)
                acc[c] = fma(wrow[c], x, acc[c]);
        }
    }

    #pragma unroll
    for (int c = 0; c < 16; ++c) {
        size_t row = (((size_t)b * Co_total + co0 + c) * Ho + h) * Wo + w;
        z[row * TPAD + t] = acc[c];
    }
}

// ---------------------------------------------------------------------------
// PSP + scan over z.  Lane = row; z reads are compulsory-BW-bound (r9 PMC).
// v2: spikes accumulated as BITS in registers, then LDS transpose ->
// coalesced u32 stores (old scattered 4-B stores were ~10x write-amplified).
// ---------------------------------------------------------------------------
__global__ __launch_bounds__(256) void psp_scan_kernel(
    const double* __restrict__ z, uint8_t* __restrict__ sout, int N)
{
    __shared__ uint32_t bits[256 * 11];   // [lane][10 words + pad]
    const int tid = threadIdx.x;
    const int n0 = blockIdx.x * 256;
    const int n = n0 + tid;
    const bool active = (n < N);

    if (active) {
        const double* zr = z + (size_t)n * TPAD;
        const IIRC c = iirc_make();
        IIRS st; iirs_init(st);
        uint32_t bw = 0;
        #pragma unroll 5
        for (int t0 = 0; t0 < 100; t0 += 4) {
            double2 xa = *(const double2*)(zr + t0);
            double2 xb = *(const double2*)(zr + t0 + 2);
            if (iir_step(c, st, xa.x, 0.0)) bw |= 1u << (t0 & 31);
            if (iir_step(c, st, xa.y, 0.0)) bw |= 1u << ((t0 + 1) & 31);
            if (iir_step(c, st, xb.x, 0.0)) bw |= 1u << ((t0 + 2) & 31);
            if (iir_step(c, st, xb.y, 0.0)) bw |= 1u << ((t0 + 3) & 31);
            if ((t0 & 31) == 28) { bits[tid * 11 + (t0 >> 5)] = bw; bw = 0; }
        }
        #pragma unroll 5
        for (int t0 = 100; t0 < TREAL; t0 += 4) {
            double2 xa = *(const double2*)(zr + t0);
            double2 xb = *(const double2*)(zr + t0 + 2);
            double2 da = *(const double2*)(zr + t0 - 100);
            double2 db = *(const double2*)(zr + t0 - 98);
            if (iir_step(c, st, xa.x, da.x)) bw |= 1u << (t0 & 31);
            if (iir_step(c, st, xa.y, da.y)) bw |= 1u << ((t0 + 1) & 31);
            if (iir_step(c, st, xb.x, db.x)) bw |= 1u << ((t0 + 2) & 31);
            if (iir_step(c, st, xb.y, db.y)) bw |= 1u << ((t0 + 3) & 31);
            if ((t0 & 31) == 28) { bits[tid * 11 + (t0 >> 5)] = bw; bw = 0; }
        }
        bits[tid * 11 + 9] = bw;   // word 9: t 288..299 set, 300..319 zero
    }
    __syncthreads();

    // coalesced unpack: task = (nl, word w in [0,80)) -> u32 of 4 spike bytes
    for (int task = tid; task < 256 * 80; task += 256) {
        int nl = task / 80, w = task - nl * 80;
        int ng = n0 + nl;
        if (ng >= N) continue;
        int tb = w * 4;
        uint32_t word = bits[nl * 11 + (tb >> 5)];
        uint32_t o = 0;
        #pragma unroll
        for (int j = 0; j < 4; ++j)
            if ((word >> ((tb + j) & 31)) & 1u) o |= 1u << (8 * j);
        *(uint32_t*)(sout + (size_t)ng * TPAD + tb) = o;
    }
}

// ---------------------------------------------------------------------------
// Pool + PSP + scan v2.  Block = 128 output neurons, 256 threads.
// Phase 1: LDS cnt tile via coalesced u32 loads (byte-wise add of 4 rows;
// counts <=4, no carries).  Phase 2: lanes 0-127 scan from LDS (stride 324 B
// -> conflict-free), spikes as register bits.  Phase 3: coalesced unpack.
// Old version: 1.98 GB HBM fetch vs 84 MB footprint (L1/L2 thrash).
// ---------------------------------------------------------------------------
template<int C, int Hi>
__global__ __launch_bounds__(256) void pool_psp_v2_kernel(
    const uint8_t* __restrict__ sprev, uint8_t* __restrict__ sout, int N)
{
    constexpr int Wi = Hi, Ho = Hi / 2, Wo = Wi / 2;
    __shared__ uint32_t cnt[128 * 81];    // [nl][80 words + pad]: stride 324 B
    __shared__ uint32_t bits[128 * 11];   // [nl][10 words + pad]
    const int tid = threadIdx.x;
    const int n0 = blockIdx.x * 128;

    // phase 1: cnt tile (all 320 t)
    for (int task = tid; task < 128 * 80; task += 256) {
        int nl = task / 80, w = task - nl * 80;
        int n = n0 + nl;
        if (n >= N) continue;
        int wo = n % Wo;  int r1 = n / Wo;
        int ho = r1 % Ho; int r2 = r1 / Ho;
        int cc = r2 % C;  int b  = r2 / C;
        const uint8_t* p0 = sprev +
            ((((size_t)b * C + cc) * Hi + 2 * ho) * Wi + 2 * wo) * TPAD + w * 4;
        uint32_t a0 = *(const uint32_t*)p0;
        uint32_t a1 = *(const uint32_t*)(p0 + TPAD);
        uint32_t a2 = *(const uint32_t*)(p0 + (size_t)Wi * TPAD);
        uint32_t a3 = *(const uint32_t*)(p0 + (size_t)(Wi + 1) * TPAD);
        cnt[nl * 81 + w] = a0 + a1 + a2 + a3;   // byte-wise counts (<=4, no carry)
    }
    __syncthreads();

    // phase 2: scan (lanes 0-127)
    if (tid < 128 && n0 + tid < N) {
        const uint8_t* cb = (const uint8_t*)cnt + (size_t)tid * 324;
        const IIRC c = iirc_make();
        IIRS st; iirs_init(st);
        uint32_t bw = 0;
        for (int t = 0; t < 100; ++t) {
            double x = POOL_W * (double)cb[t];
            if (iir_step(c, st, x, 0.0)) bw |= 1u << (t & 31);
            if ((t & 31) == 31) { bits[tid * 11 + (t >> 5)] = bw; bw = 0; }
        }
        for (int t = 100; t < TREAL; ++t) {
            double x  = POOL_W * (double)cb[t];
            double xd = POOL_W * (double)cb[t - 100];
            if (iir_step(c, st, x, xd)) bw |= 1u << (t & 31);
            if ((t & 31) == 31) { bits[tid * 11 + (t >> 5)] = bw; bw = 0; }
        }
        bits[tid * 11 + 9] = bw;   // word 9 partial (t 288..299)
    }
    __syncthreads();

    // phase 3: coalesced unpack + store (pad t>=300 written as zeros)
    for (int task = tid; task < 128 * 80; task += 256) {
        int nl = task / 80, w = task - nl * 80;
        int n = n0 + nl;
        if (n >= N) continue;
        int tb = w * 4;
        uint32_t word = bits[nl * 11 + (tb >> 5)];
        uint32_t o = 0;
        #pragma unroll
        for (int j = 0; j < 4; ++j)
            if ((word >> ((tb + j) & 31)) & 1u) o |= 1u << (8 * j);
        *(uint32_t*)(sout + (size_t)n * TPAD + tb) = o;
    }
}

// ---------------------------------------------------------------------------
// Dense partials: grid (5, B, 16).  partial[p][b*10+o][t] f64 (validated r9+).
// ---------------------------------------------------------------------------
__global__ __launch_bounds__(256) void dense_partial_kernel(
    const uint8_t* __restrict__ s5, const float* __restrict__ Wf,
    double* __restrict__ partial)
{
    const int tc = blockIdx.x, b = blockIdx.y, p = blockIdx.z;
    const int tid = threadIdx.x;
    const int tl = tid & 63, slot = tid >> 6;
    const int t = tc * 64 + tl;
    const int i0 = p * 256 + slot * 64;
    double acc[10];
    #pragma unroll
    for (int o = 0; o < 10; ++o) acc[o] = 0.0;
    const uint8_t* sp = s5 + ((size_t)b * 4096 + i0) * TPAD + t;
    for (int i = 0; i < 64; ++i) {
        float f = (float)sp[(size_t)i * TPAD];
        if (__any(f != 0.f)) {
            #pragma unroll
            for (int o = 0; o < 10; ++o)
                acc[o] = fma((double)Wf[o * 4096 + i0 + i], (double)f, acc[o]);
        }
    }
    __shared__ double red[4][64][10];
    #pragma unroll
    for (int o = 0; o < 10; ++o) red[slot][tl][o] = acc[o];
    __syncthreads();
    if (slot == 0) {
        #pragma unroll
        for (int o = 0; o < 10; ++o) {
            double v = ((red[0][tl][o] + red[1][tl][o]) + red[2][tl][o]) + red[3][tl][o];
            partial[((size_t)p * 160 + (size_t)b * 10 + o) * TPAD + t] = v;
        }
    }
}

// ---------------------------------------------------------------------------
// Final: one launch, block per (b,o) row (validated rounds 9-12).
// ---------------------------------------------------------------------------
__global__ __launch_bounds__(320) void psp_out_final_kernel(
    const double* __restrict__ partial, void* __restrict__ out,
    const int* __restrict__ flag)
{
    __shared__ double xs[TPAD];
    __shared__ uint8_t sb[TREAL];
    const int n = blockIdx.x;      // 0..159
    const int t = threadIdx.x;     // 0..319
    double v = 0.0;
    #pragma unroll
    for (int p = 0; p < 16; ++p)
        v += partial[((size_t)p * 160 + n) * TPAD + t];
    xs[t] = v;
    __syncthreads();
    if (t == 0) {
        const IIRC c = iirc_make();
        IIRS st; iirs_init(st);
        for (int i = 0; i < TREAL; ++i) {
            double xd = (i >= 100) ? xs[i - 100] : 0.0;
            sb[i] = iir_step(c, st, xs[i], xd) ? 1 : 0;
        }
    }
    __syncthreads();
    if (t < TREAL) {
        size_t e = (size_t)n * TREAL + t;
        if (*flag) ((uint16_t*)out)[e] = sb[t] ? 0x3F80 : 0;
        else       ((float*)out)[e]    = sb[t] ? 1.0f : 0.0f;
    }
}

// ---------------------------------------------------------------------------
__global__ __launch_bounds__(256) void fill_kernel(float* __restrict__ out, int n, float v)
{
    int i = blockIdx.x * 256 + threadIdx.x;
    if (i < n) out[i] = v;
}

// ---------------------------------------------------------------------------
static inline size_t alignup(size_t x) { return (x + 255) & ~(size_t)255; }
static inline int pick_bg(size_t per_b, size_t budget) {
    const int cand[5] = {16, 8, 4, 2, 1};
    for (int k = 0; k < 5; ++k)
        if (per_b * (size_t)cand[k] <= budget) return cand[k];
    return 0;
}

extern "C" void kernel_launch(void* const* d_in, const int* in_sizes, int n_in,
                              void* d_out, int out_size, void* d_ws, size_t ws_size,
                              hipStream_t stream)
{
    if (n_in != 5 || in_sizes[0] != 16 * 2 * 34 * 34 * 300 || in_sizes[1] != 800 ||
        in_sizes[2] != 4608 || in_sizes[3] != 18432 || in_sizes[4] != 40960 ||
        out_size != 16 * 10 * 300) {
        fill_kernel<<<(out_size + 255) / 256, 256, 0, stream>>>((float*)d_out, out_size, 2.0e5f);
        return;
    }

    const size_t flag_sz  = alignup(sizeof(int));
    const size_t w64_sz   = alignup((size_t)(800 + 4608 + 18432) * 8);
    const size_t wf32_sz  = alignup((size_t)40960 * 4);
    const size_t sin8_sz  = alignup((size_t)16 * 2 * 34 * 34 * TPAD);
    const size_t dpart_sz = alignup((size_t)16 * 160 * TPAD * 8);
    const size_t sA_sz    = alignup((size_t)16 * 16384 * TPAD);   // s1/s3/s5 (full batch)
    const size_t sB_sz    = alignup((size_t)16 * 4096 * TPAD);    // s2/s4   (full batch)
    const size_t base_sz  = flag_sz + w64_sz + wf32_sz + sin8_sz + dpart_sz + sA_sz + sB_sz;
    if (base_sz + 256 > ws_size) {
        fill_kernel<<<(out_size + 255) / 256, 256, 0, stream>>>((float*)d_out, out_size, 1.0e5f);
        return;
    }
    const size_t zbud = ws_size - base_sz - 256;

    const size_t zb1 = (size_t)16 * 1024 * TPAD * 8;   // 41.9 MB / batch
    const size_t zb3 = (size_t)32 * 256 * TPAD * 8;    // 21.0 MB
    const size_t zb5 = (size_t)64 * 64 * TPAD * 8;     // 10.5 MB
    const int bg1 = pick_bg(zb1, zbud), bg3 = pick_bg(zb3, zbud), bg5 = pick_bg(zb5, zbud);
    if (bg1 == 0 || bg3 == 0 || bg5 == 0) {
        fill_kernel<<<(out_size + 255) / 256, 256, 0, stream>>>((float*)d_out, out_size, 1.0e5f);
        return;
    }

    char* base = (char*)d_ws;
    int* flag = (int*)base;          base += flag_sz;
    double* w64 = (double*)base;     base += w64_sz;
    float* wf32 = (float*)base;      base += wf32_sz;
    uint8_t* sin8 = (uint8_t*)base;  base += sin8_sz;
    double* dpart = (double*)base;   base += dpart_sz;
    uint8_t* sA = (uint8_t*)base;    base += sA_sz;
    uint8_t* sB = (uint8_t*)base;    base += sB_sz;
    double* z64 = (double*)base;

    detect_kernel<<<1, 64, 0, stream>>>((const uint16_t*)d_in[1], flag);

    double* Wt1 = w64;                 // [1][50][16]
    double* Wt2 = w64 + 800;           // [2][144][16]
    double* Wt3 = w64 + 800 + 4608;    // [4][288][16]
    wtrans_kernel<<<(800 + 255) / 256, 256, 0, stream>>>(d_in[1], Wt1, 16, 50, flag);
    wtrans_kernel<<<(4608 + 255) / 256, 256, 0, stream>>>(d_in[2], Wt2, 32, 144, flag);
    wtrans_kernel<<<(18432 + 255) / 256, 256, 0, stream>>>(d_in[3], Wt3, 64, 288, flag);
    wcvt_kernel<<<(40960 + 255) / 256, 256, 0, stream>>>(d_in[4], wf32, 40960, flag);
    convert_kernel<<<16 * 2 * 34 * 34, 320, 0, stream>>>(d_in[0], sin8, flag);

    // L1: conv 2->16, 5x5 pad1, 34->32 (z-chunked) + psp scan
    for (int b0 = 0; b0 < 16; b0 += bg1) {
        conv_z_kernel<2, 2, 5, 34><<<dim3(1024, 1, bg1), 320, 0, stream>>>(
            sin8 + (size_t)b0 * 2 * 34 * 34 * TPAD, Wt1, z64, 16);
        int N = bg1 * 16384;
        psp_scan_kernel<<<(N + 255) / 256, 256, 0, stream>>>(
            z64, sA + (size_t)b0 * 16384 * TPAD, N);
    }
    // L2: pool 32->16 (+psp+scan), coalesced v2
    pool_psp_v2_kernel<16, 32><<<(16 * 4096 + 127) / 128, 256, 0, stream>>>(
        sA, sB, 16 * 4096);
    // L3: conv 16->32, 3x3 pad1, 16->16
    for (int b0 = 0; b0 < 16; b0 += bg3) {
        conv_z_kernel<16, 16, 3, 16><<<dim3(256, 2, bg3), 320, 0, stream>>>(
            sB + (size_t)b0 * 16 * 256 * TPAD, Wt2, z64, 32);
        int N = bg3 * 8192;
        psp_scan_kernel<<<(N + 255) / 256, 256, 0, stream>>>(
            z64, sA + (size_t)b0 * 8192 * TPAD, N);
    }
    // L4: pool 16->8, coalesced v2
    pool_psp_v2_kernel<32, 16><<<(16 * 2048 + 127) / 128, 256, 0, stream>>>(
        sA, sB, 16 * 2048);
    // L5: conv 32->64, 3x3 pad1, 8->8 (two 16-ci staging passes)
    for (int b0 = 0; b0 < 16; b0 += bg5) {
        conv_z_kernel<32, 16, 3, 8><<<dim3(64, 4, bg5), 320, 0, stream>>>(
            sB + (size_t)b0 * 32 * 64 * TPAD, Wt3, z64, 64);
        int N = bg5 * 4096;
        psp_scan_kernel<<<(N + 255) / 256, 256, 0, stream>>>(
            z64, sA + (size_t)b0 * 4096 * TPAD, N);
    }
    // L6: dense partials + single final scan
    dense_partial_kernel<<<dim3(5, 16, 16), 256, 0, stream>>>(sA, wf32, dpart);
    psp_out_final_kernel<<<160, 320, 0, stream>>>(dpart, d_out, flag);
}

// Round 14
// 2063.723 us; speedup vs baseline: 2.0774x; 1.1958x over previous
//
#include <hip/hip_runtime.h>
#include <hip/hip_bf16.h>
#include <stdint.h>
#include <stddef.h>

#define TPAD 320   // padded time stride (300 real + 20 pad)
#define TREAL 300

// Python-f64 pool weight: float(1.1*10.0)  (validated exact, rounds 7-13)
#define POOL_W   11.000000000000002

static __device__ __forceinline__ float bf2f(uint16_t b) {
    return __uint_as_float(((uint32_t)b) << 16);
}

// ---------------------------------------------------------------------------
// f64 truncated-alpha IIR + refractory scan (validated exact, rounds 8-13).
// ---------------------------------------------------------------------------
struct IIRC { double DD, C1, C2, C3, DR; };
static __device__ __forceinline__ IIRC iirc_make() {
    IIRC c;
    c.DD = exp(-0.1);
    c.C1 = exp(1.0) / 10.0;
    c.C2 = exp(-9.0) / 10.0;
    c.C3 = 10.0 * exp(-9.0);
    c.DR = exp(-1.0);
    return c;
}
struct IIRS { double P, Q, P2, Q2, r; };
static __device__ __forceinline__ void iirs_init(IIRS& s) {
    s.P = 0.0; s.Q = 0.0; s.P2 = 0.0; s.Q2 = 0.0; s.r = 0.0;
}
static __device__ __forceinline__ bool iir_step(const IIRC& c, IIRS& st,
                                                double x, double xd) {
    double Qn  = c.DD * (st.Q + st.P);
    double Pn  = fma(c.DD, st.P, x);
    double Q2n = c.DD * (st.Q2 + st.P2);
    double P2n = fma(c.DD, st.P2, xd);
    double a = c.C1 * Qn - c.C2 * Q2n - c.C3 * P2n;
    double u = a + st.r;
    bool s = (u >= 10.0);
    st.r = c.DR * (st.r - (s ? 20.0 : 0.0));
    st.P = Pn; st.Q = Qn; st.P2 = P2n; st.Q2 = Q2n;
    return s;
}

// ---------------------------------------------------------------------------
__global__ void detect_kernel(const uint16_t* __restrict__ w1raw, int* __restrict__ flag)
{
    if (threadIdx.x == 0 && blockIdx.x == 0) {
        int sane = 1;
        for (int i = 0; i < 800; ++i) {
            int e = (w1raw[i] >> 7) & 0xFF;
            if (e >= 131) { sane = 0; break; }
        }
        *flag = sane;   // 1 = bf16, 0 = f32
    }
}

// Conv weights -> f64, transposed to [co_group][tap][16 co-in-group].
__global__ __launch_bounds__(256) void wtrans_kernel(
    const void* __restrict__ w, double* __restrict__ out, int Co, int CKK,
    const int* __restrict__ flag)
{
    int i = blockIdx.x * 256 + threadIdx.x;
    if (i >= Co * CKK) return;
    int co = i / CKK, r = i - co * CKK;
    double v = (*flag) ? (double)bf2f(((const uint16_t*)w)[i])
                       : (double)((const float*)w)[i];
    out[(size_t)(co >> 4) * CKK * 16 + (size_t)r * 16 + (co & 15)] = v;
}

// Dense weights -> f32 (bf16->f32 exact)
__global__ __launch_bounds__(256) void wcvt_kernel(
    const void* __restrict__ w, float* __restrict__ out, int n, const int* __restrict__ flag)
{
    int i = blockIdx.x * 256 + threadIdx.x;
    if (i >= n) return;
    out[i] = (*flag) ? bf2f(((const uint16_t*)w)[i]) : ((const float*)w)[i];
}

__global__ __launch_bounds__(320) void convert_kernel(
    const void* __restrict__ s_in, uint8_t* __restrict__ u8, const int* __restrict__ flag)
{
    int row = blockIdx.x;
    int t = threadIdx.x;
    uint8_t v = 0;
    if (t < TREAL) {
        float x = (*flag) ? bf2f(((const uint16_t*)s_in)[(size_t)row * TREAL + t])
                          : ((const float*)s_in)[(size_t)row * TREAL + t];
        v = (x >= 0.5f) ? 1 : 0;
    }
    u8[(size_t)row * TPAD + t] = v;
}

// ---------------------------------------------------------------------------
// Conv -> z (f64), PIXEL-PAIR version: block = (h, w-pair, 16-co group, b).
// Two adjacent output columns share the staged halo AND each tap's 16
// weights: one s_load feeds 32 FMAs (round-13 blocks were overhead-bound:
// L3 and L5 dispatches took equal time despite 2x FMA difference).
// FMA order per accumulator identical to round 13 -> bitwise-identical z.
// Grid: (Ho*Wo/2, Co_total/16, Bg)
// ---------------------------------------------------------------------------
template<int Ci, int CIB, int K, int Hi>
__global__ __launch_bounds__(320) void conv_z_kernel(
    const uint8_t* __restrict__ sprev,   // chunk-local [Bg][Ci][Hi][Wi][TPAD]
    const double* __restrict__ Wt,       // [Co/16][CKK][16] f64 (exact bf16)
    double* __restrict__ z,              // chunk-local [Bg][Co][Ho][Wo][TPAD]
    int Co_total)
{
    constexpr int P = 1;
    constexpr int Wi = Hi;
    constexpr int Ho = Hi + 2 * P - K + 1;
    constexpr int Wo = Ho;
    constexpr int KK = K * K;
    constexpr int CKK = Ci * KK;
    constexpr int CW = K + 1;             // staged columns for the pair
    constexpr int NROW = CIB * K * CW;    // staged 320-B rows per pass
    constexpr int NPASS = Ci / CIB;
    static_assert(Ci % CIB == 0, "pass split");
    static_assert(Wo % 2 == 0, "pair split");
    static_assert(NROW * 320 <= 60 * 1024, "LDS over limit");

    __shared__ uint32_t stage[NROW * 80];

    const int t   = threadIdx.x;             // 0..319
    const int h   = (int)blockIdx.x / (Wo / 2);
    const int w   = ((int)blockIdx.x % (Wo / 2)) * 2;
    const int gy  = (int)blockIdx.y;
    const int co0 = gy * 16;
    const int b   = (int)blockIdx.z;

    double acc0[16], acc1[16];
    #pragma unroll
    for (int c = 0; c < 16; ++c) { acc0[c] = 0.0; acc1[c] = 0.0; }

    const size_t in_b = (size_t)b * Ci * Hi * Wi * TPAD;
    const double* wg = Wt + (size_t)gy * CKK * 16;

    for (int p = 0; p < NPASS; ++p) {
        const int ci0 = p * CIB;
        __syncthreads();
        for (int idx = t; idx < NROW * 80; idx += 320) {
            int r  = idx / 80, dw = idx - (idx / 80) * 80;      // const-div: cheap
            int cl = r / (K * CW);
            int rem = r - cl * (K * CW);
            int ky = rem / CW, cx = rem - ky * CW;
            int row = h - P + ky;
            int col = w - P + cx;
            uint32_t v = 0;
            if ((unsigned)row < (unsigned)Hi && (unsigned)col < (unsigned)Wi)
                v = *(const uint32_t*)(sprev + in_b +
                      (((size_t)(ci0 + cl) * Hi + row) * Wi + col) * TPAD + dw * 4);
            stage[(size_t)r * 80 + dw] = v;
        }
        __syncthreads();

        const uint8_t* sbytes = (const uint8_t*)stage;
        #pragma unroll 2
        for (int cl = 0; cl < CIB; ++cl) {
            #pragma unroll
            for (int ky = 0; ky < K; ++ky) {
                #pragma unroll
                for (int kx = 0; kx < K; ++kx) {
                    const int rbase = ((cl * K + ky) * CW + kx) * 320;
                    double x0 = (double)sbytes[rbase + t];
                    double x1 = (double)sbytes[rbase + 320 + t];
                    const double* wrow = wg +
                        ((size_t)((ci0 + cl) * KK + ky * K + kx)) * 16;  // uniform -> s_load
                    #pragma unroll
                    for (int c = 0; c < 16; ++c) {
                        double wv = wrow[c];
                        acc0[c] = fma(wv, x0, acc0[c]);
                        acc1[c] = fma(wv, x1, acc1[c]);
                    }
                }
            }
        }
    }

    #pragma unroll
    for (int c = 0; c < 16; ++c) {
        size_t row0 = (((size_t)b * Co_total + co0 + c) * Ho + h) * Wo + w;
        z[row0 * TPAD + t]          = acc0[c];
        z[(row0 + 1) * TPAD + t]    = acc1[c];
    }
}

// ---------------------------------------------------------------------------
// PSP + scan over z (validated r13): lane = row, bits-in-registers ->
// LDS transpose -> coalesced u32 stores.
// ---------------------------------------------------------------------------
__global__ __launch_bounds__(256) void psp_scan_kernel(
    const double* __restrict__ z, uint8_t* __restrict__ sout, int N)
{
    __shared__ uint32_t bits[256 * 11];
    const int tid = threadIdx.x;
    const int n0 = blockIdx.x * 256;
    const int n = n0 + tid;
    const bool active = (n < N);

    if (active) {
        const double* zr = z + (size_t)n * TPAD;
        const IIRC c = iirc_make();
        IIRS st; iirs_init(st);
        uint32_t bw = 0;
        #pragma unroll 5
        for (int t0 = 0; t0 < 100; t0 += 4) {
            double2 xa = *(const double2*)(zr + t0);
            double2 xb = *(const double2*)(zr + t0 + 2);
            if (iir_step(c, st, xa.x, 0.0)) bw |= 1u << (t0 & 31);
            if (iir_step(c, st, xa.y, 0.0)) bw |= 1u << ((t0 + 1) & 31);
            if (iir_step(c, st, xb.x, 0.0)) bw |= 1u << ((t0 + 2) & 31);
            if (iir_step(c, st, xb.y, 0.0)) bw |= 1u << ((t0 + 3) & 31);
            if ((t0 & 31) == 28) { bits[tid * 11 + (t0 >> 5)] = bw; bw = 0; }
        }
        #pragma unroll 5
        for (int t0 = 100; t0 < TREAL; t0 += 4) {
            double2 xa = *(const double2*)(zr + t0);
            double2 xb = *(const double2*)(zr + t0 + 2);
            double2 da = *(const double2*)(zr + t0 - 100);
            double2 db = *(const double2*)(zr + t0 - 98);
            if (iir_step(c, st, xa.x, da.x)) bw |= 1u << (t0 & 31);
            if (iir_step(c, st, xa.y, da.y)) bw |= 1u << ((t0 + 1) & 31);
            if (iir_step(c, st, xb.x, db.x)) bw |= 1u << ((t0 + 2) & 31);
            if (iir_step(c, st, xb.y, db.y)) bw |= 1u << ((t0 + 3) & 31);
            if ((t0 & 31) == 28) { bits[tid * 11 + (t0 >> 5)] = bw; bw = 0; }
        }
        bits[tid * 11 + 9] = bw;
    }
    __syncthreads();

    for (int task = tid; task < 256 * 80; task += 256) {
        int nl = task / 80, w = task - nl * 80;
        int ng = n0 + nl;
        if (ng >= N) continue;
        int tb = w * 4;
        uint32_t word = bits[nl * 11 + (tb >> 5)];
        uint32_t o = 0;
        #pragma unroll
        for (int j = 0; j < 4; ++j)
            if ((word >> ((tb + j) & 31)) & 1u) o |= 1u << (8 * j);
        *(uint32_t*)(sout + (size_t)ng * TPAD + tb) = o;
    }
}

// ---------------------------------------------------------------------------
// Pool + PSP + scan v2 (validated r13): LDS cnt tile, coalesced in/out.
// ---------------------------------------------------------------------------
template<int C, int Hi>
__global__ __launch_bounds__(256) void pool_psp_v2_kernel(
    const uint8_t* __restrict__ sprev, uint8_t* __restrict__ sout, int N)
{
    constexpr int Wi = Hi, Ho = Hi / 2, Wo = Wi / 2;
    __shared__ uint32_t cnt[128 * 81];
    __shared__ uint32_t bits[128 * 11];
    const int tid = threadIdx.x;
    const int n0 = blockIdx.x * 128;

    for (int task = tid; task < 128 * 80; task += 256) {
        int nl = task / 80, w = task - nl * 80;
        int n = n0 + nl;
        if (n >= N) continue;
        int wo = n % Wo;  int r1 = n / Wo;
        int ho = r1 % Ho; int r2 = r1 / Ho;
        int cc = r2 % C;  int b  = r2 / C;
        const uint8_t* p0 = sprev +
            ((((size_t)b * C + cc) * Hi + 2 * ho) * Wi + 2 * wo) * TPAD + w * 4;
        uint32_t a0 = *(const uint32_t*)p0;
        uint32_t a1 = *(const uint32_t*)(p0 + TPAD);
        uint32_t a2 = *(const uint32_t*)(p0 + (size_t)Wi * TPAD);
        uint32_t a3 = *(const uint32_t*)(p0 + (size_t)(Wi + 1) * TPAD);
        cnt[nl * 81 + w] = a0 + a1 + a2 + a3;
    }
    __syncthreads();

    if (tid < 128 && n0 + tid < N) {
        const uint8_t* cb = (const uint8_t*)cnt + (size_t)tid * 324;
        const IIRC c = iirc_make();
        IIRS st; iirs_init(st);
        uint32_t bw = 0;
        for (int t = 0; t < 100; ++t) {
            double x = POOL_W * (double)cb[t];
            if (iir_step(c, st, x, 0.0)) bw |= 1u << (t & 31);
            if ((t & 31) == 31) { bits[tid * 11 + (t >> 5)] = bw; bw = 0; }
        }
        for (int t = 100; t < TREAL; ++t) {
            double x  = POOL_W * (double)cb[t];
            double xd = POOL_W * (double)cb[t - 100];
            if (iir_step(c, st, x, xd)) bw |= 1u << (t & 31);
            if ((t & 31) == 31) { bits[tid * 11 + (t >> 5)] = bw; bw = 0; }
        }
        bits[tid * 11 + 9] = bw;
    }
    __syncthreads();

    for (int task = tid; task < 128 * 80; task += 256) {
        int nl = task / 80, w = task - nl * 80;
        int n = n0 + nl;
        if (n >= N) continue;
        int tb = w * 4;
        uint32_t word = bits[nl * 11 + (tb >> 5)];
        uint32_t o = 0;
        #pragma unroll
        for (int j = 0; j < 4; ++j)
            if ((word >> ((tb + j) & 31)) & 1u) o |= 1u << (8 * j);
        *(uint32_t*)(sout + (size_t)n * TPAD + tb) = o;
    }
}

// ---------------------------------------------------------------------------
// Dense partials: grid (5, B, 16) (validated r9+).
// ---------------------------------------------------------------------------
__global__ __launch_bounds__(256) void dense_partial_kernel(
    const uint8_t* __restrict__ s5, const float* __restrict__ Wf,
    double* __restrict__ partial)
{
    const int tc = blockIdx.x, b = blockIdx.y, p = blockIdx.z;
    const int tid = threadIdx.x;
    const int tl = tid & 63, slot = tid >> 6;
    const int t = tc * 64 + tl;
    const int i0 = p * 256 + slot * 64;
    double acc[10];
    #pragma unroll
    for (int o = 0; o < 10; ++o) acc[o] = 0.0;
    const uint8_t* sp = s5 + ((size_t)b * 4096 + i0) * TPAD + t;
    for (int i = 0; i < 64; ++i) {
        float f = (float)sp[(size_t)i * TPAD];
        if (__any(f != 0.f)) {
            #pragma unroll
            for (int o = 0; o < 10; ++o)
                acc[o] = fma((double)Wf[o * 4096 + i0 + i], (double)f, acc[o]);
        }
    }
    __shared__ double red[4][64][10];
    #pragma unroll
    for (int o = 0; o < 10; ++o) red[slot][tl][o] = acc[o];
    __syncthreads();
    if (slot == 0) {
        #pragma unroll
        for (int o = 0; o < 10; ++o) {
            double v = ((red[0][tl][o] + red[1][tl][o]) + red[2][tl][o]) + red[3][tl][o];
            partial[((size_t)p * 160 + (size_t)b * 10 + o) * TPAD + t] = v;
        }
    }
}

// ---------------------------------------------------------------------------
// Final: one launch, block per (b,o) row (validated rounds 9-13).
// ---------------------------------------------------------------------------
__global__ __launch_bounds__(320) void psp_out_final_kernel(
    const double* __restrict__ partial, void* __restrict__ out,
    const int* __restrict__ flag)
{
    __shared__ double xs[TPAD];
    __shared__ uint8_t sb[TREAL];
    const int n = blockIdx.x;
    const int t = threadIdx.x;
    double v = 0.0;
    #pragma unroll
    for (int p = 0; p < 16; ++p)
        v += partial[((size_t)p * 160 + n) * TPAD + t];
    xs[t] = v;
    __syncthreads();
    if (t == 0) {
        const IIRC c = iirc_make();
        IIRS st; iirs_init(st);
        for (int i = 0; i < TREAL; ++i) {
            double xd = (i >= 100) ? xs[i - 100] : 0.0;
            sb[i] = iir_step(c, st, xs[i], xd) ? 1 : 0;
        }
    }
    __syncthreads();
    if (t < TREAL) {
        size_t e = (size_t)n * TREAL + t;
        if (*flag) ((uint16_t*)out)[e] = sb[t] ? 0x3F80 : 0;
        else       ((float*)out)[e]    = sb[t] ? 1.0f : 0.0f;
    }
}

// ---------------------------------------------------------------------------
__global__ __launch_bounds__(256) void fill_kernel(float* __restrict__ out, int n, float v)
{
    int i = blockIdx.x * 256 + threadIdx.x;
    if (i < n) out[i] = v;
}

// ---------------------------------------------------------------------------
static inline size_t alignup(size_t x) { return (x + 255) & ~(size_t)255; }
static inline int pick_bg(size_t per_b, size_t budget) {
    const int cand[5] = {16, 8, 4, 2, 1};
    for (int k = 0; k < 5; ++k)
        if (per_b * (size_t)cand[k] <= budget) return cand[k];
    return 0;
}

extern "C" void kernel_launch(void* const* d_in, const int* in_sizes, int n_in,
                              void* d_out, int out_size, void* d_ws, size_t ws_size,
                              hipStream_t stream)
{
    if (n_in != 5 || in_sizes[0] != 16 * 2 * 34 * 34 * 300 || in_sizes[1] != 800 ||
        in_sizes[2] != 4608 || in_sizes[3] != 18432 || in_sizes[4] != 40960 ||
        out_size != 16 * 10 * 300) {
        fill_kernel<<<(out_size + 255) / 256, 256, 0, stream>>>((float*)d_out, out_size, 2.0e5f);
        return;
    }

    const size_t flag_sz  = alignup(sizeof(int));
    const size_t w64_sz   = alignup((size_t)(800 + 4608 + 18432) * 8);
    const size_t wf32_sz  = alignup((size_t)40960 * 4);
    const size_t sin8_sz  = alignup((size_t)16 * 2 * 34 * 34 * TPAD);
    const size_t dpart_sz = alignup((size_t)16 * 160 * TPAD * 8);
    const size_t sA_sz    = alignup((size_t)16 * 16384 * TPAD);
    const size_t sB_sz    = alignup((size_t)16 * 4096 * TPAD);
    const size_t base_sz  = flag_sz + w64_sz + wf32_sz + sin8_sz + dpart_sz + sA_sz + sB_sz;
    if (base_sz + 256 > ws_size) {
        fill_kernel<<<(out_size + 255) / 256, 256, 0, stream>>>((float*)d_out, out_size, 1.0e5f);
        return;
    }
    const size_t zbud = ws_size - base_sz - 256;

    const size_t zb1 = (size_t)16 * 1024 * TPAD * 8;
    const size_t zb3 = (size_t)32 * 256 * TPAD * 8;
    const size_t zb5 = (size_t)64 * 64 * TPAD * 8;
    const int bg1 = pick_bg(zb1, zbud), bg3 = pick_bg(zb3, zbud), bg5 = pick_bg(zb5, zbud);
    if (bg1 == 0 || bg3 == 0 || bg5 == 0) {
        fill_kernel<<<(out_size + 255) / 256, 256, 0, stream>>>((float*)d_out, out_size, 1.0e5f);
        return;
    }

    char* base = (char*)d_ws;
    int* flag = (int*)base;          base += flag_sz;
    double* w64 = (double*)base;     base += w64_sz;
    float* wf32 = (float*)base;      base += wf32_sz;
    uint8_t* sin8 = (uint8_t*)base;  base += sin8_sz;
    double* dpart = (double*)base;   base += dpart_sz;
    uint8_t* sA = (uint8_t*)base;    base += sA_sz;
    uint8_t* sB = (uint8_t*)base;    base += sB_sz;
    double* z64 = (double*)base;

    detect_kernel<<<1, 64, 0, stream>>>((const uint16_t*)d_in[1], flag);

    double* Wt1 = w64;                 // [1][50][16]
    double* Wt2 = w64 + 800;           // [2][144][16]
    double* Wt3 = w64 + 800 + 4608;    // [4][288][16]
    wtrans_kernel<<<(800 + 255) / 256, 256, 0, stream>>>(d_in[1], Wt1, 16, 50, flag);
    wtrans_kernel<<<(4608 + 255) / 256, 256, 0, stream>>>(d_in[2], Wt2, 32, 144, flag);
    wtrans_kernel<<<(18432 + 255) / 256, 256, 0, stream>>>(d_in[3], Wt3, 64, 288, flag);
    wcvt_kernel<<<(40960 + 255) / 256, 256, 0, stream>>>(d_in[4], wf32, 40960, flag);
    convert_kernel<<<16 * 2 * 34 * 34, 320, 0, stream>>>(d_in[0], sin8, flag);

    // L1: conv 2->16, 5x5 pad1, 34->32 (pixel-pair; stage 19.2 KB)
    for (int b0 = 0; b0 < 16; b0 += bg1) {
        conv_z_kernel<2, 2, 5, 34><<<dim3(32 * 16, 1, bg1), 320, 0, stream>>>(
            sin8 + (size_t)b0 * 2 * 34 * 34 * TPAD, Wt1, z64, 16);
        int N = bg1 * 16384;
        psp_scan_kernel<<<(N + 255) / 256, 256, 0, stream>>>(
            z64, sA + (size_t)b0 * 16384 * TPAD, N);
    }
    // L2: pool 32->16, coalesced v2
    pool_psp_v2_kernel<16, 32><<<(16 * 4096 + 127) / 128, 256, 0, stream>>>(
        sA, sB, 16 * 4096);
    // L3: conv 16->32, 3x3 pad1, 16->16 (pixel-pair; CIB=8, 2 passes, 30.7 KB)
    for (int b0 = 0; b0 < 16; b0 += bg3) {
        conv_z_kernel<16, 8, 3, 16><<<dim3(16 * 8, 2, bg3), 320, 0, stream>>>(
            sB + (size_t)b0 * 16 * 256 * TPAD, Wt2, z64, 32);
        int N = bg3 * 8192;
        psp_scan_kernel<<<(N + 255) / 256, 256, 0, stream>>>(
            z64, sA + (size_t)b0 * 8192 * TPAD, N);
    }
    // L4: pool 16->8, coalesced v2
    pool_psp_v2_kernel<32, 16><<<(16 * 2048 + 127) / 128, 256, 0, stream>>>(
        sA, sB, 16 * 2048);
    // L5: conv 32->64, 3x3 pad1, 8->8 (pixel-pair; CIB=8, 4 passes)
    for (int b0 = 0; b0 < 16; b0 += bg5) {
        conv_z_kernel<32, 8, 3, 8><<<dim3(8 * 4, 4, bg5), 320, 0, stream>>>(
            sB + (size_t)b0 * 32 * 64 * TPAD, Wt3, z64, 64);
        int N = bg5 * 4096;
        psp_scan_kernel<<<(N + 255) / 256, 256, 0, stream>>>(
            z64, sA + (size_t)b0 * 4096 * TPAD, N);
    }
    // L6: dense partials + single final scan
    dense_partial_kernel<<<dim3(5, 16, 16), 256, 0, stream>>>(sA, wf32, dpart);
    psp_out_final_kernel<<<160, 320, 0, stream>>>(dpart, d_out, flag);
}